// Round 1
// baseline (577.467 us; speedup 1.0000x reference)
//
#include <hip/hip_runtime.h>
#include <cstdint>
#include <cstddef>

#define NHEADS 16
#define HDIM   128
#define BATCH  2
#define SEQ    2048
#define DMODEL 2048
#define MTOT   (BATCH*SEQ)     // 4096
#define NQKV   (3*DMODEL)      // 6144

typedef __attribute__((ext_vector_type(8))) __bf16 bf16x8;
typedef __attribute__((ext_vector_type(4))) float f32x4;
typedef __attribute__((ext_vector_type(8))) unsigned short ushort8v;

__device__ __forceinline__ unsigned short f2bf(float f){
  uint32_t u = __float_as_uint(f);
  u = (u + 0x7fffu + ((u >> 16) & 1u)) >> 16;   // RNE
  return (unsigned short)u;
}
__device__ __forceinline__ float bf2f(unsigned short s){
  return __uint_as_float(((uint32_t)s) << 16);
}
// async global->LDS, 16B per lane; LDS dest is wave-uniform base (+lane*16 by HW)
__device__ __forceinline__ void gload_lds16(const void* src, void* lds_base){
  __builtin_amdgcn_global_load_lds((const __attribute__((address_space(1))) unsigned int*)src,
                                   (__attribute__((address_space(3))) unsigned int*)lds_base,
                                   16, 0, 0);
}

// ---------------- cast fp32 -> bf16 ----------------
__global__ void cast_kernel(const float* __restrict__ src, unsigned short* __restrict__ dst, int n){
  for (int i = (blockIdx.x*blockDim.x + threadIdx.x)*8; i < n; i += gridDim.x*blockDim.x*8){
    float4 a = *reinterpret_cast<const float4*>(src + i);
    float4 b = *reinterpret_cast<const float4*>(src + i + 4);
    ushort8v o;
    o[0]=f2bf(a.x); o[1]=f2bf(a.y); o[2]=f2bf(a.z); o[3]=f2bf(a.w);
    o[4]=f2bf(b.x); o[5]=f2bf(b.y); o[6]=f2bf(b.z); o[7]=f2bf(b.w);
    *reinterpret_cast<ushort8v*>(dst + i) = o;
  }
}

// ---------------- m97-style B^T GEMM, 128x128 tile, BK=32 ----------------
// C[m,n] = sum_k A[m,k] * Bw[n,k].  MODE 0: scatter epilogue to q/k/(v^T) head
// layouts (bf16).  MODE 1: plain fp32 C write.
template<int MODE>
__global__ __launch_bounds__(256) void gemm_bt(
    const unsigned short* __restrict__ A,
    const unsigned short* __restrict__ Bw,
    float* __restrict__ Cf,
    unsigned short* __restrict__ qo,
    unsigned short* __restrict__ ko,
    unsigned short* __restrict__ vo,
    int M, int N, int K)
{
  __shared__ __align__(16) unsigned short As[128*32];
  __shared__ __align__(16) unsigned short Bs[128*32];
  const int lane = threadIdx.x & 63;
  const int wid  = threadIdx.x >> 6;
  const int m0 = blockIdx.y * 128;
  const int n0 = blockIdx.x * 128;
  const int wr = wid >> 1, wc = wid & 1;     // 2x2 wave grid, 64x64 each

  f32x4 acc[4][4];
  #pragma unroll
  for (int i=0;i<4;++i)
    #pragma unroll
    for (int j=0;j<4;++j) acc[i][j] = (f32x4){0.f,0.f,0.f,0.f};

  const int sr  = lane >> 2;          // staging row within 16-row chunk
  const int scb = (lane & 3) << 4;    // staging col byte within 64B row

  for (int kt = 0; kt < (K >> 5); ++kt){
    const int k0 = kt << 5;
    __syncthreads();
    // stage: 2 issues/wave for A and B (1024B each). LDS linear, source col
    // pre-XORed so logical (row,c) lives at LDS (row, c ^ ((row&3)<<4)).
    #pragma unroll
    for (int i=0;i<2;++i){
      const int rloc = ((wid<<1)+i)*16 + sr;
      const int cb = scb ^ ((rloc & 3) << 4);
      gload_lds16(A  + (size_t)(m0+rloc)*K + k0 + (cb>>1), As + ((wid<<1)+i)*512);
      gload_lds16(Bw + (size_t)(n0+rloc)*K + k0 + (cb>>1), Bs + ((wid<<1)+i)*512);
    }
    __syncthreads();

    bf16x8 af[4], bfv[4];
    #pragma unroll
    for (int t=0;t<4;++t){
      const int ra = wr*64 + t*16 + (lane & 15);
      const int ca = (((lane>>4)<<4) ^ ((ra&3)<<4)) >> 1;
      af[t]  = *reinterpret_cast<const bf16x8*>(As + ra*32 + ca);
      const int rb = wc*64 + t*16 + (lane & 15);
      const int cbb = (((lane>>4)<<4) ^ ((rb&3)<<4)) >> 1;
      bfv[t] = *reinterpret_cast<const bf16x8*>(Bs + rb*32 + cbb);
    }
    #pragma unroll
    for (int i=0;i<4;++i)
      #pragma unroll
      for (int j=0;j<4;++j)
        acc[i][j] = __builtin_amdgcn_mfma_f32_16x16x32_bf16(af[i], bfv[j], acc[i][j], 0,0,0);
  }

  #pragma unroll
  for (int i=0;i<4;++i){
    const int row0 = m0 + wr*64 + i*16 + ((lane>>4)<<2);
    #pragma unroll
    for (int j=0;j<4;++j){
      const int col = n0 + wc*64 + j*16 + (lane & 15);
      f32x4 v = acc[i][j];
      if (MODE == 1){
        #pragma unroll
        for (int r=0;r<4;++r) Cf[(size_t)(row0+r)*N + col] = v[r];
      } else {
        const int part = col >> 11;       // 0=q 1=k 2=v
        const int hh = (col >> 7) & 15;
        const int d  = col & 127;
        const int bb = row0 >> 11;
        const int ss = row0 & 2047;
        if (part == 0){
          unsigned short* base = qo + ((size_t)(bb*NHEADS+hh)*SEQ + ss)*HDIM + d;
          #pragma unroll
          for (int r=0;r<4;++r) base[r*HDIM] = f2bf(v[r]);
        } else if (part == 1){
          unsigned short* base = ko + ((size_t)(bb*NHEADS+hh)*SEQ + ss)*HDIM + d;
          #pragma unroll
          for (int r=0;r<4;++r) base[r*HDIM] = f2bf(v[r]);
        } else {
          ushort4 p;           // V stored transposed: vT[b,h,d,s]; 4 consecutive s
          p.x = f2bf(v[0]); p.y = f2bf(v[1]); p.z = f2bf(v[2]); p.w = f2bf(v[3]);
          *reinterpret_cast<ushort4*>(vo + ((size_t)(bb*NHEADS+hh)*HDIM + d)*SEQ + ss) = p;
        }
      }
    }
  }
}

// ---------------- RoPE in-place on q,k (q also scaled by 1/sqrt(HD)) -------
__global__ void rope_kernel(unsigned short* __restrict__ qh, unsigned short* __restrict__ kh){
  const int idx = blockIdx.x * blockDim.x + threadIdx.x; // j(6)|s(11)|bh(5)|t(1)
  const int j  = idx & 63;
  const int s  = (idx >> 6) & 2047;
  const int bh = (idx >> 17) & 31;
  const int t  = idx >> 22;
  unsigned short* base = (t ? kh : qh) + ((size_t)bh*SEQ + s)*HDIM;
  const float x1 = bf2f(base[j]);
  const float x2 = bf2f(base[j+64]);
  // inv_freq[j] = 10000^(-j/64) = 2^(-j*log2(10000)/64)
  const float inv = exp2f(-(float)j * (13.287712379549449f/64.f));
  const float ang = (float)s * inv;
  float sn, cs;
  sincosf(ang, &sn, &cs);
  float o1 = x1*cs - x2*sn;
  float o2 = x2*cs + x1*sn;
  if (t == 0){ o1 *= 0.08838834764831845f; o2 *= 0.08838834764831845f; }
  base[j]    = f2bf(o1);
  base[j+64] = f2bf(o2);
}

// ---------------- causal flash attention ----------------
// grid (S/64 q-tiles, B*H). 4 waves x 16 q-rows. K/V staged in swizzled LDS.
__global__ __launch_bounds__(256) void attn_kernel(
    const unsigned short* __restrict__ qh,
    const unsigned short* __restrict__ kh,
    const unsigned short* __restrict__ vT,
    unsigned short* __restrict__ ao)
{
  __shared__ __align__(16) unsigned short Ks[64*128];   // [key][d], swizzled
  __shared__ __align__(16) unsigned short Vs[128*64];   // [d][key], swizzled
  __shared__ __align__(16) unsigned short Ps[4][16*64]; // per-wave P tile, swizzled

  const int lane = threadIdx.x & 63;
  const int wid  = threadIdx.x >> 6;
  const int qt = blockIdx.x;
  const int bh = blockIdx.y;
  const int b_ = bh >> 4, h_ = bh & 15;

  const unsigned short* Qb = qh + (size_t)bh * SEQ * HDIM;
  const unsigned short* Kb = kh + (size_t)bh * SEQ * HDIM;
  const unsigned short* Vb = vT + (size_t)bh * HDIM * SEQ;
  const int qrow0 = qt*64 + wid*16;

  bf16x8 qf[4];
  {
    const int qr = qrow0 + (lane & 15);
    #pragma unroll
    for (int ks = 0; ks < 4; ++ks)
      qf[ks] = *reinterpret_cast<const bf16x8*>(Qb + (size_t)qr*HDIM + ks*32 + ((lane>>4)<<3));
  }

  f32x4 oacc[8];
  #pragma unroll
  for (int t=0;t<8;++t) oacc[t] = (f32x4){0.f,0.f,0.f,0.f};
  float mrun[4] = {-3.0e38f,-3.0e38f,-3.0e38f,-3.0e38f};
  float lrun[4] = {0.f,0.f,0.f,0.f};
  const float LOG2E = 1.4426950408889634f;

  for (int kt = 0; kt <= qt; ++kt){
    __syncthreads();
    #pragma unroll
    for (int i=0;i<4;++i){            // K tile: 64x128, rows 256B, swz bits 4-6
      const int r  = (wid*4+i)*4 + (lane>>4);
      const int cb = ((lane&15)<<4) ^ ((r&7)<<4);
      gload_lds16(Kb + (size_t)(kt*64 + r)*HDIM + (cb>>1), Ks + (wid*4+i)*512);
    }
    #pragma unroll
    for (int i=0;i<4;++i){            // V^T tile: 128x64, rows 128B
      const int d  = (wid*4+i)*8 + (lane>>3);
      const int cb = ((lane&7)<<4) ^ ((d&7)<<4);
      gload_lds16(Vb + (size_t)d*SEQ + kt*64 + (cb>>1), Vs + (wid*4+i)*512);
    }
    __syncthreads();

    // S = Q K^T  (16 q-rows x 64 keys)
    f32x4 sacc[4];
    #pragma unroll
    for (int nt=0;nt<4;++nt) sacc[nt] = (f32x4){0.f,0.f,0.f,0.f};
    #pragma unroll
    for (int nt=0;nt<4;++nt){
      const int krow = nt*16 + (lane&15);
      #pragma unroll
      for (int ks=0;ks<4;++ks){
        const int cb = (ks*64 + ((lane>>4)<<4)) ^ ((krow&7)<<4);
        bf16x8 kf = *reinterpret_cast<const bf16x8*>(Ks + krow*128 + (cb>>1));
        sacc[nt] = __builtin_amdgcn_mfma_f32_16x16x32_bf16(qf[ks], kf, sacc[nt], 0,0,0);
      }
    }

    if (kt == qt){                      // causal mask on diagonal tile
      #pragma unroll
      for (int nt=0;nt<4;++nt){
        const int key = kt*64 + nt*16 + (lane&15);
        #pragma unroll
        for (int r=0;r<4;++r){
          const int qr = qrow0 + ((lane>>4)<<2) + r;
          if (key > qr) sacc[nt][r] = -1.0e30f;
        }
      }
    }

    // online softmax (rows live across 16-lane groups)
    float fac[4];
    #pragma unroll
    for (int r=0;r<4;++r){
      float mx = fmaxf(fmaxf(sacc[0][r], sacc[1][r]), fmaxf(sacc[2][r], sacc[3][r]));
      #pragma unroll
      for (int off=1; off<16; off<<=1) mx = fmaxf(mx, __shfl_xor(mx, off));
      const float mnew = fmaxf(mrun[r], mx);
      fac[r] = exp2f((mrun[r] - mnew) * LOG2E);
      mrun[r] = mnew;
      float ps = 0.f;
      #pragma unroll
      for (int nt=0;nt<4;++nt){
        const float p = exp2f((sacc[nt][r] - mnew) * LOG2E);
        sacc[nt][r] = p;
        ps += p;
      }
      #pragma unroll
      for (int off=1; off<16; off<<=1) ps += __shfl_xor(ps, off);
      lrun[r] = lrun[r]*fac[r] + ps;
    }
    #pragma unroll
    for (int t=0;t<8;++t)
      #pragma unroll
      for (int r=0;r<4;++r) oacc[t][r] *= fac[r];

    // P (bf16) -> per-wave LDS, swizzled rows of 128B
    {
      char* pb = (char*)&Ps[wid][0];
      #pragma unroll
      for (int nt=0;nt<4;++nt){
        const int keyb = (nt*16 + (lane&15)) << 1;
        #pragma unroll
        for (int r=0;r<4;++r){
          const int prow = ((lane>>4)<<2) + r;
          *(unsigned short*)(pb + prow*128 + (keyb ^ ((prow&7)<<4))) = f2bf(sacc[nt][r]);
        }
      }
    }
    __syncthreads();

    // O += P @ V
    {
      const char* pb = (const char*)&Ps[wid][0];
      const int prow = lane & 15;
      #pragma unroll
      for (int ks=0;ks<2;++ks){
        const int pcb = (ks*64 + ((lane>>4)<<4)) ^ ((prow&7)<<4);
        bf16x8 pa = *reinterpret_cast<const bf16x8*>(pb + prow*128 + pcb);
        #pragma unroll
        for (int t=0;t<8;++t){
          const int drow = t*16 + (lane&15);
          const int vcb = (ks*64 + ((lane>>4)<<4)) ^ ((drow&7)<<4);
          bf16x8 vb = *reinterpret_cast<const bf16x8*>(Vs + drow*64 + (vcb>>1));
          oacc[t] = __builtin_amdgcn_mfma_f32_16x16x32_bf16(pa, vb, oacc[t], 0,0,0);
        }
      }
    }
  }

  #pragma unroll
  for (int r=0;r<4;++r) lrun[r] = 1.0f / lrun[r];
  #pragma unroll
  for (int t=0;t<8;++t){
    const int col = h_*HDIM + t*16 + (lane&15);
    #pragma unroll
    for (int r=0;r<4;++r){
      const int s_ = qrow0 + ((lane>>4)<<2) + r;
      ao[(size_t)(b_*SEQ + s_)*DMODEL + col] = f2bf(oacc[t][r] * lrun[r]);
    }
  }
}

// ---------------- launch ----------------
extern "C" void kernel_launch(void* const* d_in, const int* in_sizes, int n_in,
                              void* d_out, int out_size, void* d_ws, size_t ws_size,
                              hipStream_t stream)
{
  const float* x     = (const float*)d_in[0];
  const float* w_qkv = (const float*)d_in[1];
  const float* w_out = (const float*)d_in[2];
  float* out = (float*)d_out;

  unsigned short* xb    = (unsigned short*)d_ws;                 // 4096x2048
  unsigned short* wqkvb = xb    + (size_t)MTOT*DMODEL;           // 6144x2048
  unsigned short* woutb = wqkvb + (size_t)NQKV*DMODEL;           // 2048x2048
  unsigned short* qhb   = woutb + (size_t)DMODEL*DMODEL;         // (B,H,S,D)
  unsigned short* khb   = qhb   + (size_t)MTOT*DMODEL;           // (B,H,S,D)
  unsigned short* vtb   = khb   + (size_t)MTOT*DMODEL;           // (B,H,D,S)
  unsigned short* aob   = vtb   + (size_t)MTOT*DMODEL;           // 4096x2048
  // total ws use: 112 MB

  hipLaunchKernelGGL(cast_kernel, dim3(1024), dim3(256), 0, stream, x,     xb,    MTOT*DMODEL);
  hipLaunchKernelGGL(cast_kernel, dim3(1024), dim3(256), 0, stream, w_qkv, wqkvb, NQKV*DMODEL);
  hipLaunchKernelGGL(cast_kernel, dim3(512),  dim3(256), 0, stream, w_out, woutb, DMODEL*DMODEL);
  hipLaunchKernelGGL((gemm_bt<0>), dim3(NQKV/128, MTOT/128), dim3(256), 0, stream,
                     xb, wqkvb, (float*)nullptr, qhb, khb, vtb, MTOT, NQKV, DMODEL);
  hipLaunchKernelGGL(rope_kernel, dim3((2*BATCH*NHEADS*SEQ*64)/256), dim3(256), 0, stream, qhb, khb);
  hipLaunchKernelGGL(attn_kernel, dim3(SEQ/64, BATCH*NHEADS), dim3(256), 0, stream, qhb, khb, vtb, aob);
  hipLaunchKernelGGL((gemm_bt<1>), dim3(DMODEL/128, MTOT/128), dim3(256), 0, stream,
                     aob, woutb, out, (unsigned short*)nullptr, (unsigned short*)nullptr,
                     (unsigned short*)nullptr, MTOT, DMODEL, DMODEL);
}

// Round 2
// 381.103 us; speedup vs baseline: 1.5153x; 1.5153x over previous
//
#include <hip/hip_runtime.h>
#include <cstdint>
#include <cstddef>

#define NHEADS 16
#define HDIM   128
#define BATCH  2
#define SEQ    2048
#define DMODEL 2048
#define MTOT   (BATCH*SEQ)     // 4096
#define NQKV   (3*DMODEL)      // 6144
#define QBLK   128

typedef __attribute__((ext_vector_type(8))) __bf16 bf16x8;
typedef __attribute__((ext_vector_type(4))) float f32x4;
typedef __attribute__((ext_vector_type(8))) unsigned short ushort8v;

__device__ __forceinline__ unsigned short f2bf(float f){
  uint32_t u = __float_as_uint(f);
  u = (u + 0x7fffu + ((u >> 16) & 1u)) >> 16;   // RNE
  return (unsigned short)u;
}
__device__ __forceinline__ float bf2f(unsigned short s){
  return __uint_as_float(((uint32_t)s) << 16);
}
// async global->LDS, 16B per lane; LDS dest is wave-uniform base (+lane*16 by HW)
__device__ __forceinline__ void gload_lds16(const void* src, void* lds_base){
  __builtin_amdgcn_global_load_lds((const __attribute__((address_space(1))) unsigned int*)src,
                                   (__attribute__((address_space(3))) unsigned int*)lds_base,
                                   16, 0, 0);
}

// ---------------- cast fp32 -> bf16 ----------------
__global__ void cast_kernel(const float* __restrict__ src, unsigned short* __restrict__ dst, int n){
  for (int i = (blockIdx.x*blockDim.x + threadIdx.x)*8; i < n; i += gridDim.x*blockDim.x*8){
    float4 a = *reinterpret_cast<const float4*>(src + i);
    float4 b = *reinterpret_cast<const float4*>(src + i + 4);
    ushort8v o;
    o[0]=f2bf(a.x); o[1]=f2bf(a.y); o[2]=f2bf(a.z); o[3]=f2bf(a.w);
    o[4]=f2bf(b.x); o[5]=f2bf(b.y); o[6]=f2bf(b.z); o[7]=f2bf(b.w);
    *reinterpret_cast<ushort8v*>(dst + i) = o;
  }
}

// ---------------- m97-style B^T GEMM, 128x128 tile, BK=32 ----------------
template<int MODE>
__global__ __launch_bounds__(256) void gemm_bt(
    const unsigned short* __restrict__ A,
    const unsigned short* __restrict__ Bw,
    float* __restrict__ Cf,
    unsigned short* __restrict__ qo,
    unsigned short* __restrict__ ko,
    unsigned short* __restrict__ vo,
    int M, int N, int K)
{
  __shared__ __align__(16) unsigned short As[128*32];
  __shared__ __align__(16) unsigned short Bs[128*32];
  const int lane = threadIdx.x & 63;
  const int wid  = threadIdx.x >> 6;
  const int m0 = blockIdx.y * 128;
  const int n0 = blockIdx.x * 128;
  const int wr = wid >> 1, wc = wid & 1;

  f32x4 acc[4][4];
  #pragma unroll
  for (int i=0;i<4;++i)
    #pragma unroll
    for (int j=0;j<4;++j) acc[i][j] = (f32x4){0.f,0.f,0.f,0.f};

  const int sr  = lane >> 2;
  const int scb = (lane & 3) << 4;

  for (int kt = 0; kt < (K >> 5); ++kt){
    const int k0 = kt << 5;
    __syncthreads();
    #pragma unroll
    for (int i=0;i<2;++i){
      const int rloc = ((wid<<1)+i)*16 + sr;
      const int cb = scb ^ ((rloc & 3) << 4);
      gload_lds16(A  + (size_t)(m0+rloc)*K + k0 + (cb>>1), As + ((wid<<1)+i)*512);
      gload_lds16(Bw + (size_t)(n0+rloc)*K + k0 + (cb>>1), Bs + ((wid<<1)+i)*512);
    }
    __syncthreads();

    bf16x8 af[4], bfv[4];
    #pragma unroll
    for (int t=0;t<4;++t){
      const int ra = wr*64 + t*16 + (lane & 15);
      const int ca = (((lane>>4)<<4) ^ ((ra&3)<<4)) >> 1;
      af[t]  = *reinterpret_cast<const bf16x8*>(As + ra*32 + ca);
      const int rb = wc*64 + t*16 + (lane & 15);
      const int cbb = (((lane>>4)<<4) ^ ((rb&3)<<4)) >> 1;
      bfv[t] = *reinterpret_cast<const bf16x8*>(Bs + rb*32 + cbb);
    }
    #pragma unroll
    for (int i=0;i<4;++i)
      #pragma unroll
      for (int j=0;j<4;++j)
        acc[i][j] = __builtin_amdgcn_mfma_f32_16x16x32_bf16(af[i], bfv[j], acc[i][j], 0,0,0);
  }

  #pragma unroll
  for (int i=0;i<4;++i){
    const int row0 = m0 + wr*64 + i*16 + ((lane>>4)<<2);
    #pragma unroll
    for (int j=0;j<4;++j){
      const int col = n0 + wc*64 + j*16 + (lane & 15);
      f32x4 v = acc[i][j];
      if (MODE == 1){
        #pragma unroll
        for (int r=0;r<4;++r) Cf[(size_t)(row0+r)*N + col] = v[r];
      } else {
        const int part = col >> 11;       // 0=q 1=k 2=v
        const int hh = (col >> 7) & 15;
        const int d  = col & 127;
        const int bb = row0 >> 11;
        const int ss = row0 & 2047;
        if (part == 0){
          unsigned short* base = qo + ((size_t)(bb*NHEADS+hh)*SEQ + ss)*HDIM + d;
          #pragma unroll
          for (int r=0;r<4;++r) base[r*HDIM] = f2bf(v[r]);
        } else if (part == 1){
          unsigned short* base = ko + ((size_t)(bb*NHEADS+hh)*SEQ + ss)*HDIM + d;
          #pragma unroll
          for (int r=0;r<4;++r) base[r*HDIM] = f2bf(v[r]);
        } else {
          ushort4 p;           // V stored transposed: vT[b,h,d,s]
          p.x = f2bf(v[0]); p.y = f2bf(v[1]); p.z = f2bf(v[2]); p.w = f2bf(v[3]);
          *reinterpret_cast<ushort4*>(vo + ((size_t)(bb*NHEADS+hh)*HDIM + d)*SEQ + ss) = p;
        }
      }
    }
  }
}

// ---------------- RoPE in-place on q,k (q also scaled by 1/sqrt(HD)) -------
__global__ void rope_kernel(unsigned short* __restrict__ qh, unsigned short* __restrict__ kh){
  const int idx = blockIdx.x * blockDim.x + threadIdx.x; // j(6)|s(11)|bh(5)|t(1)
  const int j  = idx & 63;
  const int s  = (idx >> 6) & 2047;
  const int bh = (idx >> 17) & 31;
  const int t  = idx >> 22;
  unsigned short* base = (t ? kh : qh) + ((size_t)bh*SEQ + s)*HDIM;
  const float x1 = bf2f(base[j]);
  const float x2 = bf2f(base[j+64]);
  const float inv = exp2f(-(float)j * (13.287712379549449f/64.f));
  const float ang = (float)s * inv;
  float sn, cs;
  sincosf(ang, &sn, &cs);
  float o1 = x1*cs - x2*sn;
  float o2 = x2*cs + x1*sn;
  if (t == 0){ o1 *= 0.08838834764831845f; o2 *= 0.08838834764831845f; }
  base[j]    = f2bf(o1);
  base[j+64] = f2bf(o2);
}

// ---------------- causal flash attention (v2) ----------------
// grid (S/128, B*H). 4 waves x 32 q-rows each. Double-buffered K/V in
// swizzled LDS, 2-phase schedule (stage next tile before compute, one
// barrier/tile). Per-wave P tile in LDS (no block barrier needed for it).
__global__ __launch_bounds__(256, 2) void attn_kernel(
    const unsigned short* __restrict__ qh,
    const unsigned short* __restrict__ kh,
    const unsigned short* __restrict__ vT,
    unsigned short* __restrict__ ao)
{
  __shared__ __align__(16) unsigned short Ks[2][64*128];   // [key][d], swizzled
  __shared__ __align__(16) unsigned short Vs[2][128*64];   // [d][key], swizzled
  __shared__ __align__(16) unsigned short Ps[4][32*64];    // per-wave P, swizzled

  const int lane = threadIdx.x & 63;
  const int wid  = threadIdx.x >> 6;
  const int hi   = lane >> 4;
  const int qt = blockIdx.x;
  const int bh = blockIdx.y;
  const int b_ = bh >> 4, h_ = bh & 15;

  const unsigned short* Qb = qh + (size_t)bh * SEQ * HDIM;
  const unsigned short* Kb = kh + (size_t)bh * SEQ * HDIM;
  const unsigned short* Vb = vT + (size_t)bh * HDIM * SEQ;
  const int qrow0w = qt*QBLK + wid*32;          // this wave's 32 q-rows

  // Q fragments: 2 row-frags x 4 k-slices
  bf16x8 qf[2][4];
  #pragma unroll
  for (int fi=0; fi<2; ++fi){
    const int qr = qrow0w + fi*16 + (lane & 15);
    #pragma unroll
    for (int ks = 0; ks < 4; ++ks)
      qf[fi][ks] = *reinterpret_cast<const bf16x8*>(Qb + (size_t)qr*HDIM + ks*32 + hi*8);
  }

  f32x4 oacc[2][8];
  #pragma unroll
  for (int fi=0;fi<2;++fi)
    #pragma unroll
    for (int t=0;t<8;++t) oacc[fi][t] = (f32x4){0.f,0.f,0.f,0.f};
  float mrun[2][4], lrun[2][4];
  #pragma unroll
  for (int fi=0;fi<2;++fi)
    #pragma unroll
    for (int r=0;r<4;++r){ mrun[fi][r] = -3.0e38f; lrun[fi][r] = 0.f; }
  const float LOG2E = 1.4426950408889634f;

  const int nkt = 2*qt + 2;

  // prologue: stage tile 0 into buf 0
  {
    #pragma unroll
    for (int i=0;i<4;++i){
      const int r  = (wid*4+i)*4 + (lane>>4);
      const int cb = ((lane&15)<<4) ^ ((r&7)<<4);
      gload_lds16(Kb + (size_t)r*HDIM + (cb>>1), &Ks[0][0] + (wid*4+i)*512);
    }
    #pragma unroll
    for (int i=0;i<4;++i){
      const int d  = (wid*4+i)*8 + (lane>>3);
      const int cb = ((lane&7)<<4) ^ ((d&7)<<4);
      gload_lds16(Vb + (size_t)d*SEQ + (cb>>1), &Vs[0][0] + (wid*4+i)*512);
    }
  }
  __syncthreads();

  for (int kt = 0; kt < nkt; ++kt){
    const int cur = kt & 1;
    // 2-phase: issue next tile's stage first; loads fly during compute
    if (kt + 1 < nkt){
      const int kg = kt + 1;
      #pragma unroll
      for (int i=0;i<4;++i){
        const int r  = (wid*4+i)*4 + (lane>>4);
        const int cb = ((lane&15)<<4) ^ ((r&7)<<4);
        gload_lds16(Kb + (size_t)(kg*64 + r)*HDIM + (cb>>1), &Ks[cur^1][0] + (wid*4+i)*512);
      }
      #pragma unroll
      for (int i=0;i<4;++i){
        const int d  = (wid*4+i)*8 + (lane>>3);
        const int cb = ((lane&7)<<4) ^ ((d&7)<<4);
        gload_lds16(Vb + (size_t)d*SEQ + kg*64 + (cb>>1), &Vs[cur^1][0] + (wid*4+i)*512);
      }
    }

    // skip tiles fully above the diagonal for this wave (barrier still hit)
    if (kt*64 <= qrow0w + 31){
      // ---- S = Q K^T : 2 frags x 64 keys ----
      f32x4 sacc[2][4];
      #pragma unroll
      for (int fi=0;fi<2;++fi)
        #pragma unroll
        for (int nt=0;nt<4;++nt) sacc[fi][nt] = (f32x4){0.f,0.f,0.f,0.f};
      #pragma unroll
      for (int nt=0;nt<4;++nt){
        const int krow = nt*16 + (lane&15);
        bf16x8 kf[4];
        #pragma unroll
        for (int ks=0;ks<4;++ks){
          const int cb = (ks*64 + (hi<<4)) ^ ((krow&7)<<4);
          kf[ks] = *reinterpret_cast<const bf16x8*>(&Ks[cur][0] + krow*128 + (cb>>1));
        }
        #pragma unroll
        for (int fi=0;fi<2;++fi)
          #pragma unroll
          for (int ks=0;ks<4;++ks)
            sacc[fi][nt] = __builtin_amdgcn_mfma_f32_16x16x32_bf16(qf[fi][ks], kf[ks], sacc[fi][nt], 0,0,0);
      }

      // ---- causal mask (only tiles touching the diagonal) ----
      #pragma unroll
      for (int fi=0;fi<2;++fi){
        if (kt*64 + 63 > qrow0w + fi*16){
          #pragma unroll
          for (int nt=0;nt<4;++nt){
            const int key = kt*64 + nt*16 + (lane&15);
            #pragma unroll
            for (int r=0;r<4;++r){
              const int qr = qrow0w + fi*16 + hi*4 + r;
              if (key > qr) sacc[fi][nt][r] = -1.0e30f;
            }
          }
        }
      }

      // ---- online softmax + P write (per-wave LDS) ----
      char* pb = (char*)&Ps[wid][0];
      #pragma unroll
      for (int fi=0;fi<2;++fi){
        float fac[4];
        #pragma unroll
        for (int r=0;r<4;++r){
          float mx = fmaxf(fmaxf(sacc[fi][0][r], sacc[fi][1][r]),
                           fmaxf(sacc[fi][2][r], sacc[fi][3][r]));
          #pragma unroll
          for (int off=1; off<16; off<<=1) mx = fmaxf(mx, __shfl_xor(mx, off));
          const float mnew = fmaxf(mrun[fi][r], mx);
          fac[r] = exp2f((mrun[fi][r] - mnew) * LOG2E);
          mrun[fi][r] = mnew;
          float ps = 0.f;
          #pragma unroll
          for (int nt=0;nt<4;++nt){
            const float p = exp2f((sacc[fi][nt][r] - mnew) * LOG2E);
            sacc[fi][nt][r] = p;
            ps += p;
          }
          #pragma unroll
          for (int off=1; off<16; off<<=1) ps += __shfl_xor(ps, off);
          lrun[fi][r] = lrun[fi][r]*fac[r] + ps;
        }
        #pragma unroll
        for (int t=0;t<8;++t)
          #pragma unroll
          for (int r=0;r<4;++r) oacc[fi][t][r] *= fac[r];
        #pragma unroll
        for (int nt=0;nt<4;++nt){
          const int keyb = (nt*16 + (lane&15)) << 1;
          #pragma unroll
          for (int r=0;r<4;++r){
            const int prow = fi*16 + hi*4 + r;
            *(unsigned short*)(pb + prow*128 + (keyb ^ ((prow&7)<<4))) = f2bf(sacc[fi][nt][r]);
          }
        }
      }
      // wave-local LDS RAW: drain ds_writes before pa reads (rule #18)
      asm volatile("s_waitcnt lgkmcnt(0)" ::: "memory");
      __builtin_amdgcn_sched_barrier(0);

      // ---- O += P @ V ----
      bf16x8 pa[2][2];
      #pragma unroll
      for (int fi=0;fi<2;++fi){
        const int prow = fi*16 + (lane & 15);
        #pragma unroll
        for (int ks=0;ks<2;++ks){
          const int pcb = (ks*64 + (hi<<4)) ^ ((prow&7)<<4);
          pa[fi][ks] = *reinterpret_cast<const bf16x8*>(pb + prow*128 + pcb);
        }
      }
      #pragma unroll
      for (int ks=0;ks<2;++ks){
        #pragma unroll
        for (int t=0;t<8;++t){
          const int drow = t*16 + (lane&15);
          const int vcb = (ks*64 + (hi<<4)) ^ ((drow&7)<<4);
          bf16x8 vb = *reinterpret_cast<const bf16x8*>(&Vs[cur][0] + drow*64 + (vcb>>1));
          #pragma unroll
          for (int fi=0;fi<2;++fi)
            oacc[fi][t] = __builtin_amdgcn_mfma_f32_16x16x32_bf16(pa[fi][ks], vb, oacc[fi][t], 0,0,0);
        }
      }
    }

    // one barrier per tile: drains next-tile vmcnt AND protects buffers
    __syncthreads();
  }

  #pragma unroll
  for (int fi=0;fi<2;++fi){
    float linv[4];
    #pragma unroll
    for (int r=0;r<4;++r) linv[r] = 1.0f / lrun[fi][r];
    #pragma unroll
    for (int t=0;t<8;++t){
      const int col = h_*HDIM + t*16 + (lane&15);
      #pragma unroll
      for (int r=0;r<4;++r){
        const int s_ = qrow0w + fi*16 + hi*4 + r;
        ao[(size_t)(b_*SEQ + s_)*DMODEL + col] = f2bf(oacc[fi][t][r] * linv[r]);
      }
    }
  }
}

// ---------------- launch ----------------
extern "C" void kernel_launch(void* const* d_in, const int* in_sizes, int n_in,
                              void* d_out, int out_size, void* d_ws, size_t ws_size,
                              hipStream_t stream)
{
  const float* x     = (const float*)d_in[0];
  const float* w_qkv = (const float*)d_in[1];
  const float* w_out = (const float*)d_in[2];
  float* out = (float*)d_out;

  unsigned short* xb    = (unsigned short*)d_ws;                 // 4096x2048
  unsigned short* wqkvb = xb    + (size_t)MTOT*DMODEL;           // 6144x2048
  unsigned short* woutb = wqkvb + (size_t)NQKV*DMODEL;           // 2048x2048
  unsigned short* qhb   = woutb + (size_t)DMODEL*DMODEL;         // (B,H,S,D)
  unsigned short* khb   = qhb   + (size_t)MTOT*DMODEL;           // (B,H,S,D)
  unsigned short* vtb   = khb   + (size_t)MTOT*DMODEL;           // (B,H,D,S)
  unsigned short* aob   = vtb   + (size_t)MTOT*DMODEL;           // 4096x2048

  hipLaunchKernelGGL(cast_kernel, dim3(1024), dim3(256), 0, stream, x,     xb,    MTOT*DMODEL);
  hipLaunchKernelGGL(cast_kernel, dim3(1024), dim3(256), 0, stream, w_qkv, wqkvb, NQKV*DMODEL);
  hipLaunchKernelGGL(cast_kernel, dim3(512),  dim3(256), 0, stream, w_out, woutb, DMODEL*DMODEL);
  hipLaunchKernelGGL((gemm_bt<0>), dim3(NQKV/128, MTOT/128), dim3(256), 0, stream,
                     xb, wqkvb, (float*)nullptr, qhb, khb, vtb, MTOT, NQKV, DMODEL);
  hipLaunchKernelGGL(rope_kernel, dim3((2*BATCH*NHEADS*SEQ*64)/256), dim3(256), 0, stream, qhb, khb);
  hipLaunchKernelGGL(attn_kernel, dim3(SEQ/QBLK, BATCH*NHEADS), dim3(256), 0, stream, qhb, khb, vtb, aob);
  hipLaunchKernelGGL((gemm_bt<1>), dim3(DMODEL/128, MTOT/128), dim3(256), 0, stream,
                     aob, woutb, out, (unsigned short*)nullptr, (unsigned short*)nullptr,
                     (unsigned short*)nullptr, MTOT, DMODEL, DMODEL);
}

// Round 3
// 319.977 us; speedup vs baseline: 1.8047x; 1.1910x over previous
//
#include <hip/hip_runtime.h>
#include <cstdint>
#include <cstddef>

#define NHEADS 16
#define HDIM   128
#define BATCH  2
#define SEQ    2048
#define DMODEL 2048
#define MTOT   (BATCH*SEQ)     // 4096
#define NQKV   (3*DMODEL)      // 6144
#define QBLK   64              // per-block q-rows per half (4 waves x 16)

typedef __attribute__((ext_vector_type(8))) __bf16 bf16x8;
typedef __attribute__((ext_vector_type(4))) float f32x4;
typedef __attribute__((ext_vector_type(8))) unsigned short ushort8v;

__device__ __forceinline__ unsigned short f2bf(float f){
  __bf16 h = (__bf16)f;
  return __builtin_bit_cast(unsigned short, h);
}
__device__ __forceinline__ float bf2f(unsigned short s){
  return __uint_as_float(((uint32_t)s) << 16);
}
// async global->LDS, 16B per lane; LDS dest is wave-uniform base (+lane*16 by HW)
__device__ __forceinline__ void gload_lds16(const void* src, void* lds_base){
  __builtin_amdgcn_global_load_lds((const __attribute__((address_space(1))) unsigned int*)src,
                                   (__attribute__((address_space(3))) unsigned int*)lds_base,
                                   16, 0, 0);
}

// DPP move within 16-lane rows (row_ror). ror(N) mod 16 forms a rotation
// butterfly: 4 steps give every lane the full 16-lane reduction, ~VALU cost
// (vs ~120cy/hop for ds_bpermute-based __shfl_xor).
template<int CTRL>
__device__ __forceinline__ float dppmv(float x){
  return __uint_as_float((unsigned)__builtin_amdgcn_update_dpp(
      0, (int)__float_as_uint(x), CTRL, 0xF, 0xF, true));
}
__device__ __forceinline__ float rmax16(float x){
  x = fmaxf(x, dppmv<0x128>(x));   // row_ror:8
  x = fmaxf(x, dppmv<0x124>(x));   // row_ror:4
  x = fmaxf(x, dppmv<0x122>(x));   // row_ror:2
  x = fmaxf(x, dppmv<0x121>(x));   // row_ror:1
  return x;
}
__device__ __forceinline__ float rsum16(float x){
  x += dppmv<0x128>(x);
  x += dppmv<0x124>(x);
  x += dppmv<0x122>(x);
  x += dppmv<0x121>(x);
  return x;
}

// ---------------- cast fp32 -> bf16 ----------------
__global__ void cast_kernel(const float* __restrict__ src, unsigned short* __restrict__ dst, int n){
  for (int i = (blockIdx.x*blockDim.x + threadIdx.x)*8; i < n; i += gridDim.x*blockDim.x*8){
    float4 a = *reinterpret_cast<const float4*>(src + i);
    float4 b = *reinterpret_cast<const float4*>(src + i + 4);
    ushort8v o;
    o[0]=f2bf(a.x); o[1]=f2bf(a.y); o[2]=f2bf(a.z); o[3]=f2bf(a.w);
    o[4]=f2bf(b.x); o[5]=f2bf(b.y); o[6]=f2bf(b.z); o[7]=f2bf(b.w);
    *reinterpret_cast<ushort8v*>(dst + i) = o;
  }
}

// ---------------- m97-style B^T GEMM, 128x128 tile, BK=32 ----------------
template<int MODE>
__global__ __launch_bounds__(256) void gemm_bt(
    const unsigned short* __restrict__ A,
    const unsigned short* __restrict__ Bw,
    float* __restrict__ Cf,
    unsigned short* __restrict__ qo,
    unsigned short* __restrict__ ko,
    unsigned short* __restrict__ vo,
    int M, int N, int K)
{
  __shared__ __align__(16) unsigned short As[128*32];
  __shared__ __align__(16) unsigned short Bs[128*32];
  const int lane = threadIdx.x & 63;
  const int wid  = threadIdx.x >> 6;
  const int m0 = blockIdx.y * 128;
  const int n0 = blockIdx.x * 128;
  const int wr = wid >> 1, wc = wid & 1;

  f32x4 acc[4][4];
  #pragma unroll
  for (int i=0;i<4;++i)
    #pragma unroll
    for (int j=0;j<4;++j) acc[i][j] = (f32x4){0.f,0.f,0.f,0.f};

  const int sr  = lane >> 2;
  const int scb = (lane & 3) << 4;

  for (int kt = 0; kt < (K >> 5); ++kt){
    const int k0 = kt << 5;
    __syncthreads();
    #pragma unroll
    for (int i=0;i<2;++i){
      const int rloc = ((wid<<1)+i)*16 + sr;
      const int cb = scb ^ ((rloc & 3) << 4);
      gload_lds16(A  + (size_t)(m0+rloc)*K + k0 + (cb>>1), As + ((wid<<1)+i)*512);
      gload_lds16(Bw + (size_t)(n0+rloc)*K + k0 + (cb>>1), Bs + ((wid<<1)+i)*512);
    }
    __syncthreads();

    bf16x8 af[4], bfv[4];
    #pragma unroll
    for (int t=0;t<4;++t){
      const int ra = wr*64 + t*16 + (lane & 15);
      const int ca = (((lane>>4)<<4) ^ ((ra&3)<<4)) >> 1;
      af[t]  = *reinterpret_cast<const bf16x8*>(As + ra*32 + ca);
      const int rb = wc*64 + t*16 + (lane & 15);
      const int cbb = (((lane>>4)<<4) ^ ((rb&3)<<4)) >> 1;
      bfv[t] = *reinterpret_cast<const bf16x8*>(Bs + rb*32 + cbb);
    }
    #pragma unroll
    for (int i=0;i<4;++i)
      #pragma unroll
      for (int j=0;j<4;++j)
        acc[i][j] = __builtin_amdgcn_mfma_f32_16x16x32_bf16(af[i], bfv[j], acc[i][j], 0,0,0);
  }

  #pragma unroll
  for (int i=0;i<4;++i){
    const int row0 = m0 + wr*64 + i*16 + ((lane>>4)<<2);
    #pragma unroll
    for (int j=0;j<4;++j){
      const int col = n0 + wc*64 + j*16 + (lane & 15);
      f32x4 v = acc[i][j];
      if (MODE == 1){
        #pragma unroll
        for (int r=0;r<4;++r) Cf[(size_t)(row0+r)*N + col] = v[r];
      } else {
        const int part = col >> 11;       // 0=q 1=k 2=v
        const int hh = (col >> 7) & 15;
        const int d  = col & 127;
        const int bb = row0 >> 11;
        const int ss = row0 & 2047;
        if (part == 0){
          unsigned short* base = qo + ((size_t)(bb*NHEADS+hh)*SEQ + ss)*HDIM + d;
          #pragma unroll
          for (int r=0;r<4;++r) base[r*HDIM] = f2bf(v[r]);
        } else if (part == 1){
          unsigned short* base = ko + ((size_t)(bb*NHEADS+hh)*SEQ + ss)*HDIM + d;
          #pragma unroll
          for (int r=0;r<4;++r) base[r*HDIM] = f2bf(v[r]);
        } else {
          ushort4 p;           // V stored transposed: vT[b,h,d,s]
          p.x = f2bf(v[0]); p.y = f2bf(v[1]); p.z = f2bf(v[2]); p.w = f2bf(v[3]);
          *reinterpret_cast<ushort4*>(vo + ((size_t)(bb*NHEADS+hh)*HDIM + d)*SEQ + ss) = p;
        }
      }
    }
  }
}

// ---------------- RoPE in-place on q,k -------------------------------------
// q additionally scaled by (1/sqrt(HD)) * log2(e): attention scores come out
// of QK^T already in log2 units -> exp2 directly in softmax.
__global__ void rope_kernel(unsigned short* __restrict__ qh, unsigned short* __restrict__ kh){
  const int idx = blockIdx.x * blockDim.x + threadIdx.x; // j(6)|s(11)|bh(5)|t(1)
  const int j  = idx & 63;
  const int s  = (idx >> 6) & 2047;
  const int bh = (idx >> 17) & 31;
  const int t  = idx >> 22;
  unsigned short* base = (t ? kh : qh) + ((size_t)bh*SEQ + s)*HDIM;
  const float x1 = bf2f(base[j]);
  const float x2 = bf2f(base[j+64]);
  const float inv = exp2f(-(float)j * (13.287712379549449f/64.f));
  const float ang = (float)s * inv;
  float sn, cs;
  sincosf(ang, &sn, &cs);
  float o1 = x1*cs - x2*sn;
  float o2 = x2*cs + x1*sn;
  const float QSCALE = 0.08838834764831845f * 1.4426950408889634f;
  if (t == 0){ o1 *= QSCALE; o2 *= QSCALE; }
  base[j]    = f2bf(o1);
  base[j+64] = f2bf(o2);
}

// ---------------- causal flash attention (v3) ----------------
// grid (16 pairs, B*H). Block handles q-tiles {pr, 31-pr} sequentially
// (uniform 33 KV-tiles/block -> perfect balance). 4 waves x 16 q-rows.
// Double-buffered K/V in swizzled LDS (72KB -> 2 blocks/CU), DPP softmax.
__global__ __launch_bounds__(256, 2) void attn_kernel(
    const unsigned short* __restrict__ qh,
    const unsigned short* __restrict__ kh,
    const unsigned short* __restrict__ vT,
    unsigned short* __restrict__ ao)
{
  __shared__ __align__(16) unsigned short Ks[2][64*128];   // [key][d], swizzled
  __shared__ __align__(16) unsigned short Vs[2][128*64];   // [d][key], swizzled
  __shared__ __align__(16) unsigned short Ps[4][16*64];    // per-wave P, swizzled

  const int lane = threadIdx.x & 63;
  const int wid  = threadIdx.x >> 6;
  const int hi   = lane >> 4;
  const int pr = blockIdx.x;          // pair index 0..15
  const int bh = blockIdx.y;
  const int b_ = bh >> 4, h_ = bh & 15;

  const unsigned short* Qb = qh + (size_t)bh * SEQ * HDIM;
  const unsigned short* Kb = kh + (size_t)bh * SEQ * HDIM;
  const unsigned short* Vb = vT + (size_t)bh * HDIM * SEQ;

  auto stageKV = [&](int kg, int buf){
    #pragma unroll
    for (int i=0;i<4;++i){
      const int r  = (wid*4+i)*4 + (lane>>4);
      const int cb = ((lane&15)<<4) ^ ((r&7)<<4);
      gload_lds16(Kb + (size_t)(kg*64 + r)*HDIM + (cb>>1), &Ks[buf][0] + (wid*4+i)*512);
    }
    #pragma unroll
    for (int i=0;i<4;++i){
      const int d  = (wid*4+i)*8 + (lane>>3);
      const int cb = ((lane&7)<<4) ^ ((d&7)<<4);
      gload_lds16(Vb + (size_t)d*SEQ + kg*64 + (cb>>1), &Vs[buf][0] + (wid*4+i)*512);
    }
  };

  for (int ph = 0; ph < 2; ++ph){
    const int qt = ph ? (31 - pr) : pr;
    const int qrow0w = qt*QBLK + wid*16;

    bf16x8 qf[4];
    {
      const int qr = qrow0w + (lane & 15);
      #pragma unroll
      for (int ks = 0; ks < 4; ++ks)
        qf[ks] = *reinterpret_cast<const bf16x8*>(Qb + (size_t)qr*HDIM + ks*32 + hi*8);
    }

    f32x4 oacc[8];
    #pragma unroll
    for (int t=0;t<8;++t) oacc[t] = (f32x4){0.f,0.f,0.f,0.f};
    float mrun[4] = {-3.0e38f,-3.0e38f,-3.0e38f,-3.0e38f};
    float lrun[4] = {0.f,0.f,0.f,0.f};

    const int nkt = qt + 1;

    stageKV(0, 0);
    __syncthreads();

    for (int kt = 0; kt < nkt; ++kt){
      const int cur = kt & 1;
      if (kt + 1 < nkt) stageKV(kt + 1, cur ^ 1);

      if (kt*64 <= qrow0w + 15){
        // ---- S = Q K^T ----
        f32x4 sacc[4];
        #pragma unroll
        for (int nt=0;nt<4;++nt) sacc[nt] = (f32x4){0.f,0.f,0.f,0.f};
        __builtin_amdgcn_s_setprio(1);
        #pragma unroll
        for (int nt=0;nt<4;++nt){
          const int krow = nt*16 + (lane&15);
          #pragma unroll
          for (int ks=0;ks<4;++ks){
            const int cb = (ks*64 + (hi<<4)) ^ ((krow&7)<<4);
            bf16x8 kf = *reinterpret_cast<const bf16x8*>(&Ks[cur][0] + krow*128 + (cb>>1));
            sacc[nt] = __builtin_amdgcn_mfma_f32_16x16x32_bf16(qf[ks], kf, sacc[nt], 0,0,0);
          }
        }
        __builtin_amdgcn_s_setprio(0);

        // ---- causal mask (diagonal tile only) ----
        if (kt*64 + 63 > qrow0w){
          #pragma unroll
          for (int nt=0;nt<4;++nt){
            const int key = kt*64 + nt*16 + (lane&15);
            #pragma unroll
            for (int r=0;r<4;++r){
              const int qr = qrow0w + hi*4 + r;
              if (key > qr) sacc[nt][r] = -1.0e30f;
            }
          }
        }

        // ---- online softmax (DPP reduces; scores already in log2 units) ----
        float fac[4];
        #pragma unroll
        for (int r=0;r<4;++r){
          float mx = fmaxf(fmaxf(sacc[0][r], sacc[1][r]),
                           fmaxf(sacc[2][r], sacc[3][r]));
          mx = rmax16(mx);
          const float mnew = fmaxf(mrun[r], mx);
          fac[r] = exp2f(mrun[r] - mnew);
          mrun[r] = mnew;
          float ps = 0.f;
          #pragma unroll
          for (int nt=0;nt<4;++nt){
            const float p = exp2f(sacc[nt][r] - mnew);
            sacc[nt][r] = p;
            ps += p;
          }
          ps = rsum16(ps);
          lrun[r] = lrun[r]*fac[r] + ps;
        }
        #pragma unroll
        for (int t=0;t<8;++t)
          #pragma unroll
          for (int r=0;r<4;++r) oacc[t][r] *= fac[r];

        // ---- P (bf16) -> per-wave LDS, swizzled ----
        char* pb = (char*)&Ps[wid][0];
        #pragma unroll
        for (int nt=0;nt<4;++nt){
          const int keyb = (nt*16 + (lane&15)) << 1;
          #pragma unroll
          for (int r=0;r<4;++r){
            const int prow = hi*4 + r;
            *(unsigned short*)(pb + prow*128 + (keyb ^ ((prow&7)<<4))) = f2bf(sacc[nt][r]);
          }
        }
        // wave-local LDS RAW: drain ds_writes before pa reads (rule #18)
        asm volatile("s_waitcnt lgkmcnt(0)" ::: "memory");
        __builtin_amdgcn_sched_barrier(0);

        // ---- O += P @ V ----
        bf16x8 pa[2];
        {
          const int prow = lane & 15;
          #pragma unroll
          for (int ks=0;ks<2;++ks){
            const int pcb = (ks*64 + (hi<<4)) ^ ((prow&7)<<4);
            pa[ks] = *reinterpret_cast<const bf16x8*>(pb + prow*128 + pcb);
          }
        }
        __builtin_amdgcn_s_setprio(1);
        #pragma unroll
        for (int ks=0;ks<2;++ks){
          #pragma unroll
          for (int t=0;t<8;++t){
            const int drow = t*16 + (lane&15);
            const int vcb = (ks*64 + (hi<<4)) ^ ((drow&7)<<4);
            bf16x8 vb = *reinterpret_cast<const bf16x8*>(&Vs[cur][0] + drow*64 + (vcb>>1));
            oacc[t] = __builtin_amdgcn_mfma_f32_16x16x32_bf16(pa[ks], vb, oacc[t], 0,0,0);
          }
        }
        __builtin_amdgcn_s_setprio(0);
      }

      __syncthreads();   // drains next-tile vmcnt + protects buffers
    }

    // ---- epilogue for this half ----
    float linv[4];
    #pragma unroll
    for (int r=0;r<4;++r) linv[r] = 1.0f / lrun[r];
    #pragma unroll
    for (int t=0;t<8;++t){
      const int col = h_*HDIM + t*16 + (lane&15);
      #pragma unroll
      for (int r=0;r<4;++r){
        const int s_ = qrow0w + hi*4 + r;
        ao[(size_t)(b_*SEQ + s_)*DMODEL + col] = f2bf(oacc[t][r] * linv[r]);
      }
    }
  }
}

// ---------------- launch ----------------
extern "C" void kernel_launch(void* const* d_in, const int* in_sizes, int n_in,
                              void* d_out, int out_size, void* d_ws, size_t ws_size,
                              hipStream_t stream)
{
  const float* x     = (const float*)d_in[0];
  const float* w_qkv = (const float*)d_in[1];
  const float* w_out = (const float*)d_in[2];
  float* out = (float*)d_out;

  unsigned short* xb    = (unsigned short*)d_ws;                 // 4096x2048
  unsigned short* wqkvb = xb    + (size_t)MTOT*DMODEL;           // 6144x2048
  unsigned short* woutb = wqkvb + (size_t)NQKV*DMODEL;           // 2048x2048
  unsigned short* qhb   = woutb + (size_t)DMODEL*DMODEL;         // (B,H,S,D)
  unsigned short* khb   = qhb   + (size_t)MTOT*DMODEL;           // (B,H,S,D)
  unsigned short* vtb   = khb   + (size_t)MTOT*DMODEL;           // (B,H,D,S)
  unsigned short* aob   = vtb   + (size_t)MTOT*DMODEL;           // 4096x2048

  hipLaunchKernelGGL(cast_kernel, dim3(1024), dim3(256), 0, stream, x,     xb,    MTOT*DMODEL);
  hipLaunchKernelGGL(cast_kernel, dim3(1024), dim3(256), 0, stream, w_qkv, wqkvb, NQKV*DMODEL);
  hipLaunchKernelGGL(cast_kernel, dim3(512),  dim3(256), 0, stream, w_out, woutb, DMODEL*DMODEL);
  hipLaunchKernelGGL((gemm_bt<0>), dim3(NQKV/128, MTOT/128), dim3(256), 0, stream,
                     xb, wqkvb, (float*)nullptr, qhb, khb, vtb, MTOT, NQKV, DMODEL);
  hipLaunchKernelGGL(rope_kernel, dim3((2*BATCH*NHEADS*SEQ*64)/256), dim3(256), 0, stream, qhb, khb);
  hipLaunchKernelGGL(attn_kernel, dim3(16, BATCH*NHEADS), dim3(256), 0, stream, qhb, khb, vtb, aob);
  hipLaunchKernelGGL((gemm_bt<1>), dim3(DMODEL/128, MTOT/128), dim3(256), 0, stream,
                     aob, woutb, out, (unsigned short*)nullptr, (unsigned short*)nullptr,
                     (unsigned short*)nullptr, MTOT, DMODEL, DMODEL);
}

// Round 4
// 306.998 us; speedup vs baseline: 1.8810x; 1.0423x over previous
//
#include <hip/hip_runtime.h>
#include <cstdint>
#include <cstddef>

#define NHEADS 16
#define HDIM   128
#define BATCH  2
#define SEQ    2048
#define DMODEL 2048
#define MTOT   (BATCH*SEQ)     // 4096
#define NQKV   (3*DMODEL)      // 6144
#define QBLK   64              // attn: per-block q-rows per half (4 waves x 16)

typedef __attribute__((ext_vector_type(8))) __bf16 bf16x8;
typedef __attribute__((ext_vector_type(4))) float f32x4;
typedef __attribute__((ext_vector_type(8))) unsigned short ushort8v;

__device__ __forceinline__ unsigned short f2bf(float f){
  __bf16 h = (__bf16)f;
  return __builtin_bit_cast(unsigned short, h);
}
__device__ __forceinline__ float bf2f(unsigned short s){
  return __uint_as_float(((uint32_t)s) << 16);
}
// async global->LDS, 16B per lane; LDS dest is wave-uniform base (+lane*16 by HW)
__device__ __forceinline__ void gload_lds16(const void* src, void* lds_base){
  __builtin_amdgcn_global_load_lds((const __attribute__((address_space(1))) unsigned int*)src,
                                   (__attribute__((address_space(3))) unsigned int*)lds_base,
                                   16, 0, 0);
}

// DPP 16-lane-row rotation butterflies (see round 2)
template<int CTRL>
__device__ __forceinline__ float dppmv(float x){
  return __uint_as_float((unsigned)__builtin_amdgcn_update_dpp(
      0, (int)__float_as_uint(x), CTRL, 0xF, 0xF, true));
}
__device__ __forceinline__ float rmax16(float x){
  x = fmaxf(x, dppmv<0x128>(x));
  x = fmaxf(x, dppmv<0x124>(x));
  x = fmaxf(x, dppmv<0x122>(x));
  x = fmaxf(x, dppmv<0x121>(x));
  return x;
}
__device__ __forceinline__ float rsum16(float x){
  x += dppmv<0x128>(x);
  x += dppmv<0x124>(x);
  x += dppmv<0x122>(x);
  x += dppmv<0x121>(x);
  return x;
}

// ---------------- fused cast fp32 -> bf16 (3 arrays, 1 launch) -------------
__global__ void cast3_kernel(const float* __restrict__ s0, unsigned short* __restrict__ d0, int n0,
                             const float* __restrict__ s1, unsigned short* __restrict__ d1, int n1,
                             const float* __restrict__ s2, unsigned short* __restrict__ d2, int n2){
  const int stride = gridDim.x*blockDim.x*8;
  const int base = (blockIdx.x*blockDim.x + threadIdx.x)*8;
  #pragma unroll 1
  for (int a = 0; a < 3; ++a){
    const float* s = a==0 ? s0 : (a==1 ? s1 : s2);
    unsigned short* d = a==0 ? d0 : (a==1 ? d1 : d2);
    const int n = a==0 ? n0 : (a==1 ? n1 : n2);
    for (int i = base; i < n; i += stride){
      float4 x = *reinterpret_cast<const float4*>(s + i);
      float4 y = *reinterpret_cast<const float4*>(s + i + 4);
      ushort8v o;
      o[0]=f2bf(x.x); o[1]=f2bf(x.y); o[2]=f2bf(x.z); o[3]=f2bf(x.w);
      o[4]=f2bf(y.x); o[5]=f2bf(y.y); o[6]=f2bf(y.z); o[7]=f2bf(y.w);
      *reinterpret_cast<ushort8v*>(d + i) = o;
    }
  }
}

// ---------------- 8-phase 256x256 B^T GEMM (m201-style), BK=64 -------------
// C[m,n] = sum_k A[m,k]*Bw[n,k]. 8 waves (2M x 4N), per-wave out 128x64.
// LDS: 2 buf x 4 half-tiles (A0,A1,B0,B1) x [128][64] bf16 = 128 KiB.
// Counted vmcnt(4) at tile boundary; raw s_barrier (NO full drain).
// Stage schedule per tile t: p0:t+1-B0  p1:t+1-B1  p2:t+2-A0(cur)  p3:t+2-A1(cur)
// Safety: A region consumed at p0 (all 16 frags -> regs), B at its phase.
template<int MODE>
__global__ __launch_bounds__(512, 2) void gemm8(
    const unsigned short* __restrict__ A,
    const unsigned short* __restrict__ Bw,
    float* __restrict__ Cf,
    unsigned short* __restrict__ qo,
    unsigned short* __restrict__ ko,
    unsigned short* __restrict__ vo,
    int M, int N, int K)
{
  __shared__ __align__(16) unsigned short lds[2][4][128*64];
  const int lane = threadIdx.x & 63;
  const int wid  = threadIdx.x >> 6;
  const int wm = wid >> 2, wn = wid & 3;
  const int hi = lane >> 4;

  // bijective XCD swizzle (grid size is a multiple of 8 here: 384)
  const int nwg = gridDim.x * gridDim.y;
  const int bid = blockIdx.y * gridDim.x + blockIdx.x;
  const int swz = (bid & 7) * (nwg >> 3) + (bid >> 3);
  const int by = swz & (gridDim.y - 1);          // gridDim.y = 16 (pow2)
  const int bx = swz >> 4;
  const int m0 = by * 256;
  const int n0 = bx * 256;

  const int NT = K >> 6;

  // stage one half-tile (128 rows x 64 cols) of `base` into lds[buf][ht].
  // Source col pre-XORed so logical (r, slot s) lives at LDS slot s^(r&7).
  auto stage = [&](const unsigned short* base, int row0, int k0, int buf, int ht){
    const int rlo = wid << 4;
    #pragma unroll
    for (int i=0;i<2;++i){
      const int r = rlo + i*8 + (lane>>3);
      const int csrc = ((lane&7) ^ (lane>>3)) << 3;   // elems
      gload_lds16(base + (size_t)(row0 + r)*K + k0 + csrc,
                  &lds[buf][ht][(rlo + i*8)*64]);
    }
  };
  // read one MFMA frag: row r within half, 16B slot s (s = ks*4 + hi)
  auto frag = [&](const unsigned short* h, int r, int s){
    return *reinterpret_cast<const bf16x8*>(h + r*64 + ((s ^ (r&7)) << 3));
  };

  f32x4 acc[8][4];
  #pragma unroll
  for (int i=0;i<8;++i)
    #pragma unroll
    for (int j=0;j<4;++j) acc[i][j] = (f32x4){0.f,0.f,0.f,0.f};

  // ---- prologue: t0 all 4 halves + t1-A0,A1; drain t0, keep t1-A in flight
  stage(A,  m0,      0, 0, 0);
  stage(A,  m0+128,  0, 0, 1);
  stage(Bw, n0,      0, 0, 2);
  stage(Bw, n0+128,  0, 0, 3);
  if (NT > 1){
    stage(A, m0,     64, 1, 0);
    stage(A, m0+128, 64, 1, 1);
    asm volatile("s_waitcnt vmcnt(4)" ::: "memory");
  } else {
    asm volatile("s_waitcnt vmcnt(0)" ::: "memory");
  }
  __builtin_amdgcn_sched_barrier(0);
  __builtin_amdgcn_s_barrier();

  for (int kt = 0; kt < NT; ++kt){
    const int cur = kt & 1, nxt = cur ^ 1;
    const unsigned short* Ah = &lds[cur][wm][0];
    const unsigned short* Bh = &lds[cur][2 + (wn>>1)][0];
    const int rbase = (wn & 1) * 64;

    bf16x8 Ar[8][2];
    #pragma unroll
    for (int p = 0; p < 4; ++p){
      // ---- ds reads for this phase ----
      if (p == 0){
        #pragma unroll
        for (int fm=0;fm<8;++fm)
          #pragma unroll
          for (int ks=0;ks<2;++ks)
            Ar[fm][ks] = frag(Ah, fm*16 + (lane&15), ks*4 + hi);
      }
      const int rb = rbase + p*16 + (lane&15);
      bf16x8 b0 = frag(Bh, rb, 0*4 + hi);
      bf16x8 b1 = frag(Bh, rb, 1*4 + hi);

      // ---- stage prefetches ----
      if (p == 0 && kt+1 < NT) stage(Bw, n0,      (kt+1)*64, nxt, 2);
      if (p == 1 && kt+1 < NT) stage(Bw, n0+128,  (kt+1)*64, nxt, 3);
      if (p == 2 && kt+2 < NT) stage(A,  m0,      (kt+2)*64, cur, 0);
      if (p == 3){
        if (kt+2 < NT){
          stage(A, m0+128, (kt+2)*64, cur, 1);
          asm volatile("s_waitcnt vmcnt(4)" ::: "memory");   // tile kt+1 landed
        } else if (kt+1 < NT){
          asm volatile("s_waitcnt vmcnt(0)" ::: "memory");
        }
      }
      __builtin_amdgcn_sched_barrier(0);
      __builtin_amdgcn_s_barrier();

      // ---- MFMA cluster: 16 mfma (8 m-frags x 2 k-steps), n-frag = p ----
      __builtin_amdgcn_s_setprio(1);
      #pragma unroll
      for (int fm=0;fm<8;++fm){
        acc[fm][p] = __builtin_amdgcn_mfma_f32_16x16x32_bf16(Ar[fm][0], b0, acc[fm][p], 0,0,0);
        acc[fm][p] = __builtin_amdgcn_mfma_f32_16x16x32_bf16(Ar[fm][1], b1, acc[fm][p], 0,0,0);
      }
      __builtin_amdgcn_s_setprio(0);
      __builtin_amdgcn_sched_barrier(0);
      __builtin_amdgcn_s_barrier();
    }
  }

  // ---- epilogue ----
  #pragma unroll
  for (int fm=0;fm<8;++fm){
    const int row0 = m0 + wm*128 + fm*16 + (hi<<2);
    #pragma unroll
    for (int p=0;p<4;++p){
      const int col = n0 + wn*64 + p*16 + (lane & 15);
      f32x4 v = acc[fm][p];
      if (MODE == 1){
        #pragma unroll
        for (int r=0;r<4;++r) Cf[(size_t)(row0+r)*N + col] = v[r];
      } else {
        const int part = col >> 11;       // 0=q 1=k 2=v
        const int hh = (col >> 7) & 15;
        const int d  = col & 127;
        const int bb = row0 >> 11;
        const int ss = row0 & 2047;
        if (part == 0){
          unsigned short* base = qo + ((size_t)(bb*NHEADS+hh)*SEQ + ss)*HDIM + d;
          #pragma unroll
          for (int r=0;r<4;++r) base[r*HDIM] = f2bf(v[r]);
        } else if (part == 1){
          unsigned short* base = ko + ((size_t)(bb*NHEADS+hh)*SEQ + ss)*HDIM + d;
          #pragma unroll
          for (int r=0;r<4;++r) base[r*HDIM] = f2bf(v[r]);
        } else {
          ushort4 pk;          // V stored transposed: vT[b,h,d,s]
          pk.x = f2bf(v[0]); pk.y = f2bf(v[1]); pk.z = f2bf(v[2]); pk.w = f2bf(v[3]);
          *reinterpret_cast<ushort4*>(vo + ((size_t)(bb*NHEADS+hh)*HDIM + d)*SEQ + ss) = pk;
        }
      }
    }
  }
}

// ---------------- m97-style 128x128 B^T GEMM (kept for out-proj) -----------
template<int MODE>
__global__ __launch_bounds__(256) void gemm_bt(
    const unsigned short* __restrict__ A,
    const unsigned short* __restrict__ Bw,
    float* __restrict__ Cf,
    int M, int N, int K)
{
  __shared__ __align__(16) unsigned short As[128*32];
  __shared__ __align__(16) unsigned short Bs[128*32];
  const int lane = threadIdx.x & 63;
  const int wid  = threadIdx.x >> 6;
  const int m0 = blockIdx.y * 128;
  const int n0 = blockIdx.x * 128;
  const int wr = wid >> 1, wc = wid & 1;

  f32x4 acc[4][4];
  #pragma unroll
  for (int i=0;i<4;++i)
    #pragma unroll
    for (int j=0;j<4;++j) acc[i][j] = (f32x4){0.f,0.f,0.f,0.f};

  const int sr  = lane >> 2;
  const int scb = (lane & 3) << 4;

  for (int kt = 0; kt < (K >> 5); ++kt){
    const int k0 = kt << 5;
    __syncthreads();
    #pragma unroll
    for (int i=0;i<2;++i){
      const int rloc = ((wid<<1)+i)*16 + sr;
      const int cb = scb ^ ((rloc & 3) << 4);
      gload_lds16(A  + (size_t)(m0+rloc)*K + k0 + (cb>>1), As + ((wid<<1)+i)*512);
      gload_lds16(Bw + (size_t)(n0+rloc)*K + k0 + (cb>>1), Bs + ((wid<<1)+i)*512);
    }
    __syncthreads();

    bf16x8 af[4], bfv[4];
    #pragma unroll
    for (int t=0;t<4;++t){
      const int ra = wr*64 + t*16 + (lane & 15);
      const int ca = (((lane>>4)<<4) ^ ((ra&3)<<4)) >> 1;
      af[t]  = *reinterpret_cast<const bf16x8*>(As + ra*32 + ca);
      const int rbq = wc*64 + t*16 + (lane & 15);
      const int cbb = (((lane>>4)<<4) ^ ((rbq&3)<<4)) >> 1;
      bfv[t] = *reinterpret_cast<const bf16x8*>(Bs + rbq*32 + cbb);
    }
    #pragma unroll
    for (int i=0;i<4;++i)
      #pragma unroll
      for (int j=0;j<4;++j)
        acc[i][j] = __builtin_amdgcn_mfma_f32_16x16x32_bf16(af[i], bfv[j], acc[i][j], 0,0,0);
  }

  #pragma unroll
  for (int i=0;i<4;++i){
    const int row0 = m0 + wr*64 + i*16 + ((lane>>4)<<2);
    #pragma unroll
    for (int j=0;j<4;++j){
      const int col = n0 + wc*64 + j*16 + (lane & 15);
      f32x4 v = acc[i][j];
      #pragma unroll
      for (int r=0;r<4;++r) Cf[(size_t)(row0+r)*N + col] = v[r];
    }
  }
}

// ---------------- RoPE in-place on q,k -------------------------------------
__global__ void rope_kernel(unsigned short* __restrict__ qh, unsigned short* __restrict__ kh){
  const int idx = blockIdx.x * blockDim.x + threadIdx.x; // j(6)|s(11)|bh(5)|t(1)
  const int j  = idx & 63;
  const int s  = (idx >> 6) & 2047;
  const int bh = (idx >> 17) & 31;
  const int t  = idx >> 22;
  unsigned short* base = (t ? kh : qh) + ((size_t)bh*SEQ + s)*HDIM;
  const float x1 = bf2f(base[j]);
  const float x2 = bf2f(base[j+64]);
  const float inv = exp2f(-(float)j * (13.287712379549449f/64.f));
  const float ang = (float)s * inv;
  float sn, cs;
  sincosf(ang, &sn, &cs);
  float o1 = x1*cs - x2*sn;
  float o2 = x2*cs + x1*sn;
  const float QSCALE = 0.08838834764831845f * 1.4426950408889634f;
  if (t == 0){ o1 *= QSCALE; o2 *= QSCALE; }
  base[j]    = f2bf(o1);
  base[j+64] = f2bf(o2);
}

// ---------------- causal flash attention (v3, unchanged) -------------------
__global__ __launch_bounds__(256, 2) void attn_kernel(
    const unsigned short* __restrict__ qh,
    const unsigned short* __restrict__ kh,
    const unsigned short* __restrict__ vT,
    unsigned short* __restrict__ ao)
{
  __shared__ __align__(16) unsigned short Ks[2][64*128];
  __shared__ __align__(16) unsigned short Vs[2][128*64];
  __shared__ __align__(16) unsigned short Ps[4][16*64];

  const int lane = threadIdx.x & 63;
  const int wid  = threadIdx.x >> 6;
  const int hi   = lane >> 4;
  const int pr = blockIdx.x;
  const int bh = blockIdx.y;
  const int b_ = bh >> 4, h_ = bh & 15;

  const unsigned short* Qb = qh + (size_t)bh * SEQ * HDIM;
  const unsigned short* Kb = kh + (size_t)bh * SEQ * HDIM;
  const unsigned short* Vb = vT + (size_t)bh * HDIM * SEQ;

  auto stageKV = [&](int kg, int buf){
    #pragma unroll
    for (int i=0;i<4;++i){
      const int r  = (wid*4+i)*4 + (lane>>4);
      const int cb = ((lane&15)<<4) ^ ((r&7)<<4);
      gload_lds16(Kb + (size_t)(kg*64 + r)*HDIM + (cb>>1), &Ks[buf][0] + (wid*4+i)*512);
    }
    #pragma unroll
    for (int i=0;i<4;++i){
      const int d  = (wid*4+i)*8 + (lane>>3);
      const int cb = ((lane&7)<<4) ^ ((d&7)<<4);
      gload_lds16(Vb + (size_t)d*SEQ + kg*64 + (cb>>1), &Vs[buf][0] + (wid*4+i)*512);
    }
  };

  for (int ph = 0; ph < 2; ++ph){
    const int qt = ph ? (31 - pr) : pr;
    const int qrow0w = qt*QBLK + wid*16;

    bf16x8 qf[4];
    {
      const int qr = qrow0w + (lane & 15);
      #pragma unroll
      for (int ks = 0; ks < 4; ++ks)
        qf[ks] = *reinterpret_cast<const bf16x8*>(Qb + (size_t)qr*HDIM + ks*32 + hi*8);
    }

    f32x4 oacc[8];
    #pragma unroll
    for (int t=0;t<8;++t) oacc[t] = (f32x4){0.f,0.f,0.f,0.f};
    float mrun[4] = {-3.0e38f,-3.0e38f,-3.0e38f,-3.0e38f};
    float lrun[4] = {0.f,0.f,0.f,0.f};

    const int nkt = qt + 1;

    stageKV(0, 0);
    __syncthreads();

    for (int kt = 0; kt < nkt; ++kt){
      const int cur = kt & 1;
      if (kt + 1 < nkt) stageKV(kt + 1, cur ^ 1);

      if (kt*64 <= qrow0w + 15){
        f32x4 sacc[4];
        #pragma unroll
        for (int nt=0;nt<4;++nt) sacc[nt] = (f32x4){0.f,0.f,0.f,0.f};
        __builtin_amdgcn_s_setprio(1);
        #pragma unroll
        for (int nt=0;nt<4;++nt){
          const int krow = nt*16 + (lane&15);
          #pragma unroll
          for (int ks=0;ks<4;++ks){
            const int cb = (ks*64 + (hi<<4)) ^ ((krow&7)<<4);
            bf16x8 kf = *reinterpret_cast<const bf16x8*>(&Ks[cur][0] + krow*128 + (cb>>1));
            sacc[nt] = __builtin_amdgcn_mfma_f32_16x16x32_bf16(qf[ks], kf, sacc[nt], 0,0,0);
          }
        }
        __builtin_amdgcn_s_setprio(0);

        if (kt*64 + 63 > qrow0w){
          #pragma unroll
          for (int nt=0;nt<4;++nt){
            const int key = kt*64 + nt*16 + (lane&15);
            #pragma unroll
            for (int r=0;r<4;++r){
              const int qr = qrow0w + hi*4 + r;
              if (key > qr) sacc[nt][r] = -1.0e30f;
            }
          }
        }

        float fac[4];
        #pragma unroll
        for (int r=0;r<4;++r){
          float mx = fmaxf(fmaxf(sacc[0][r], sacc[1][r]),
                           fmaxf(sacc[2][r], sacc[3][r]));
          mx = rmax16(mx);
          const float mnew = fmaxf(mrun[r], mx);
          fac[r] = exp2f(mrun[r] - mnew);
          mrun[r] = mnew;
          float ps = 0.f;
          #pragma unroll
          for (int nt=0;nt<4;++nt){
            const float p = exp2f(sacc[nt][r] - mnew);
            sacc[nt][r] = p;
            ps += p;
          }
          ps = rsum16(ps);
          lrun[r] = lrun[r]*fac[r] + ps;
        }
        #pragma unroll
        for (int t=0;t<8;++t)
          #pragma unroll
          for (int r=0;r<4;++r) oacc[t][r] *= fac[r];

        char* pb = (char*)&Ps[wid][0];
        #pragma unroll
        for (int nt=0;nt<4;++nt){
          const int keyb = (nt*16 + (lane&15)) << 1;
          #pragma unroll
          for (int r=0;r<4;++r){
            const int prow = hi*4 + r;
            *(unsigned short*)(pb + prow*128 + (keyb ^ ((prow&7)<<4))) = f2bf(sacc[nt][r]);
          }
        }
        asm volatile("s_waitcnt lgkmcnt(0)" ::: "memory");
        __builtin_amdgcn_sched_barrier(0);

        bf16x8 pa[2];
        {
          const int prow = lane & 15;
          #pragma unroll
          for (int ks=0;ks<2;++ks){
            const int pcb = (ks*64 + (hi<<4)) ^ ((prow&7)<<4);
            pa[ks] = *reinterpret_cast<const bf16x8*>(pb + prow*128 + pcb);
          }
        }
        __builtin_amdgcn_s_setprio(1);
        #pragma unroll
        for (int ks=0;ks<2;++ks){
          #pragma unroll
          for (int t=0;t<8;++t){
            const int drow = t*16 + (lane&15);
            const int vcb = (ks*64 + (hi<<4)) ^ ((drow&7)<<4);
            bf16x8 vb = *reinterpret_cast<const bf16x8*>(&Vs[cur][0] + drow*64 + (vcb>>1));
            oacc[t] = __builtin_amdgcn_mfma_f32_16x16x32_bf16(pa[ks], vb, oacc[t], 0,0,0);
          }
        }
        __builtin_amdgcn_s_setprio(0);
      }

      __syncthreads();
    }

    float linv[4];
    #pragma unroll
    for (int r=0;r<4;++r) linv[r] = 1.0f / lrun[r];
    #pragma unroll
    for (int t=0;t<8;++t){
      const int col = h_*HDIM + t*16 + (lane&15);
      #pragma unroll
      for (int r=0;r<4;++r){
        const int s_ = qrow0w + hi*4 + r;
        ao[(size_t)(b_*SEQ + s_)*DMODEL + col] = f2bf(oacc[t][r] * linv[r]);
      }
    }
  }
}

// ---------------- launch ----------------
extern "C" void kernel_launch(void* const* d_in, const int* in_sizes, int n_in,
                              void* d_out, int out_size, void* d_ws, size_t ws_size,
                              hipStream_t stream)
{
  const float* x     = (const float*)d_in[0];
  const float* w_qkv = (const float*)d_in[1];
  const float* w_out = (const float*)d_in[2];
  float* out = (float*)d_out;

  unsigned short* xb    = (unsigned short*)d_ws;                 // 4096x2048
  unsigned short* wqkvb = xb    + (size_t)MTOT*DMODEL;           // 6144x2048
  unsigned short* woutb = wqkvb + (size_t)NQKV*DMODEL;           // 2048x2048
  unsigned short* qhb   = woutb + (size_t)DMODEL*DMODEL;         // (B,H,S,D)
  unsigned short* khb   = qhb   + (size_t)MTOT*DMODEL;           // (B,H,S,D)
  unsigned short* vtb   = khb   + (size_t)MTOT*DMODEL;           // (B,H,D,S)
  unsigned short* aob   = vtb   + (size_t)MTOT*DMODEL;           // 4096x2048

  hipLaunchKernelGGL(cast3_kernel, dim3(1024), dim3(256), 0, stream,
                     x, xb, MTOT*DMODEL, w_qkv, wqkvb, NQKV*DMODEL, w_out, woutb, DMODEL*DMODEL);
  hipLaunchKernelGGL((gemm8<0>), dim3(NQKV/256, MTOT/256), dim3(512), 0, stream,
                     xb, wqkvb, (float*)nullptr, qhb, khb, vtb, MTOT, NQKV, DMODEL);
  hipLaunchKernelGGL(rope_kernel, dim3((2*BATCH*NHEADS*SEQ*64)/256), dim3(256), 0, stream, qhb, khb);
  hipLaunchKernelGGL(attn_kernel, dim3(16, BATCH*NHEADS), dim3(256), 0, stream, qhb, khb, vtb, aob);
  hipLaunchKernelGGL((gemm_bt<1>), dim3(DMODEL/128, MTOT/128), dim3(256), 0, stream,
                     aob, woutb, out, MTOT, DMODEL, DMODEL);
}

// Round 5
// 301.263 us; speedup vs baseline: 1.9168x; 1.0190x over previous
//
#include <hip/hip_runtime.h>
#include <cstdint>
#include <cstddef>

#define NHEADS 16
#define HDIM   128
#define BATCH  2
#define SEQ    2048
#define DMODEL 2048
#define MTOT   (BATCH*SEQ)     // 4096
#define NQKV   (3*DMODEL)      // 6144
#define QBLK   64              // attn: per-block q-rows per half (4 waves x 16)

typedef __attribute__((ext_vector_type(8))) __bf16 bf16x8;
typedef __attribute__((ext_vector_type(4))) float f32x4;
typedef __attribute__((ext_vector_type(8))) unsigned short ushort8v;

__device__ __forceinline__ unsigned short f2bf(float f){
  __bf16 h = (__bf16)f;
  return __builtin_bit_cast(unsigned short, h);
}
__device__ __forceinline__ float bf2f(unsigned short s){
  return __uint_as_float(((uint32_t)s) << 16);
}
// async global->LDS, 16B per lane; LDS dest is wave-uniform base (+lane*16 by HW)
__device__ __forceinline__ void gload_lds16(const void* src, void* lds_base){
  __builtin_amdgcn_global_load_lds((const __attribute__((address_space(1))) unsigned int*)src,
                                   (__attribute__((address_space(3))) unsigned int*)lds_base,
                                   16, 0, 0);
}

// DPP 16-lane-row rotation butterflies (see round 2)
template<int CTRL>
__device__ __forceinline__ float dppmv(float x){
  return __uint_as_float((unsigned)__builtin_amdgcn_update_dpp(
      0, (int)__float_as_uint(x), CTRL, 0xF, 0xF, true));
}
__device__ __forceinline__ float rmax16(float x){
  x = fmaxf(x, dppmv<0x128>(x));
  x = fmaxf(x, dppmv<0x124>(x));
  x = fmaxf(x, dppmv<0x122>(x));
  x = fmaxf(x, dppmv<0x121>(x));
  return x;
}
__device__ __forceinline__ float rsum16(float x){
  x += dppmv<0x128>(x);
  x += dppmv<0x124>(x);
  x += dppmv<0x122>(x);
  x += dppmv<0x121>(x);
  return x;
}

// ---------------- fused cast fp32 -> bf16 (3 arrays, 1 launch) -------------
__global__ void cast3_kernel(const float* __restrict__ s0, unsigned short* __restrict__ d0, int n0,
                             const float* __restrict__ s1, unsigned short* __restrict__ d1, int n1,
                             const float* __restrict__ s2, unsigned short* __restrict__ d2, int n2){
  const int stride = gridDim.x*blockDim.x*8;
  const int base = (blockIdx.x*blockDim.x + threadIdx.x)*8;
  #pragma unroll 1
  for (int a = 0; a < 3; ++a){
    const float* s = a==0 ? s0 : (a==1 ? s1 : s2);
    unsigned short* d = a==0 ? d0 : (a==1 ? d1 : d2);
    const int n = a==0 ? n0 : (a==1 ? n1 : n2);
    for (int i = base; i < n; i += stride){
      float4 x = *reinterpret_cast<const float4*>(s + i);
      float4 y = *reinterpret_cast<const float4*>(s + i + 4);
      ushort8v o;
      o[0]=f2bf(x.x); o[1]=f2bf(x.y); o[2]=f2bf(x.z); o[3]=f2bf(x.w);
      o[4]=f2bf(y.x); o[5]=f2bf(y.y); o[6]=f2bf(y.z); o[7]=f2bf(y.w);
      *reinterpret_cast<ushort8v*>(d + i) = o;
    }
  }
}

// ---------------- 256x256 B^T GEMM, BK=64, 2-phase counted-vmcnt -----------
// C[m,n] = sum_k A[m,k]*Bw[n,k]. 8 waves (2M x 4N), per-wave out 128x64.
// LDS staging: 2 buf x 4 half-tiles (A0,A1,B0,B1) x [128][64] bf16 = 128 KiB.
// Phase 0: read all 16 A-frags + B n-half0; stage B0,B1(t+1)->nxt; 32 MFMA.
// Phase 1: read B n-half1; stage A0,A1(t+2)->cur; 32 MFMA; vmcnt(4).
// Safety: A region fully in regs at p0 (barrier'd) -> overwrite at p1 ok.
// vmcnt(4) at tile end: 12 outstanding -> retire 8 = tile t+1 landed.
template<int MODE>
__global__ __launch_bounds__(512, 2) void gemm8(
    const unsigned short* __restrict__ A,
    const unsigned short* __restrict__ Bw,
    float* __restrict__ Cf,
    unsigned short* __restrict__ qo,
    unsigned short* __restrict__ ko,
    unsigned short* __restrict__ vo,
    int M, int N, int K)
{
  // 135168 B: staging view needs 131072; V-transpose view needs 256*264*2
  __shared__ __align__(16) unsigned short smem[256*264];
  auto lds = reinterpret_cast<unsigned short (*)[4][128*64]>(smem);  // [2][4][8192]

  const int lane = threadIdx.x & 63;
  const int wid  = threadIdx.x >> 6;
  const int wm = wid >> 2, wn = wid & 3;
  const int hi = lane >> 4;

  // bijective XCD swizzle (grid size 384, multiple of 8)
  const int nwg = gridDim.x * gridDim.y;
  const int bid = blockIdx.y * gridDim.x + blockIdx.x;
  const int swz = (bid & 7) * (nwg >> 3) + (bid >> 3);
  const int by = swz & (gridDim.y - 1);          // gridDim.y = 16 (pow2)
  const int bx = swz >> 4;
  const int m0 = by * 256;
  const int n0 = bx * 256;

  const int NT = K >> 6;

  auto stage = [&](const unsigned short* base, int row0, int k0, int buf, int ht){
    const int rlo = wid << 4;
    #pragma unroll
    for (int i=0;i<2;++i){
      const int r = rlo + i*8 + (lane>>3);
      const int csrc = ((lane&7) ^ (lane>>3)) << 3;   // elems
      gload_lds16(base + (size_t)(row0 + r)*K + k0 + csrc,
                  &lds[buf][ht][(rlo + i*8)*64]);
    }
  };
  auto frag = [&](const unsigned short* h, int r, int s){
    return *reinterpret_cast<const bf16x8*>(h + r*64 + ((s ^ (r&7)) << 3));
  };

  f32x4 acc[8][4];
  #pragma unroll
  for (int i=0;i<8;++i)
    #pragma unroll
    for (int j=0;j<4;++j) acc[i][j] = (f32x4){0.f,0.f,0.f,0.f};

  // ---- prologue: t0 all 4 halves + t1-A; drain t0, keep t1-A in flight ----
  stage(A,  m0,      0, 0, 0);
  stage(A,  m0+128,  0, 0, 1);
  stage(Bw, n0,      0, 0, 2);
  stage(Bw, n0+128,  0, 0, 3);
  if (NT > 1){
    stage(A, m0,     64, 1, 0);
    stage(A, m0+128, 64, 1, 1);
    asm volatile("s_waitcnt vmcnt(4)" ::: "memory");
  } else {
    asm volatile("s_waitcnt vmcnt(0)" ::: "memory");
  }
  __builtin_amdgcn_sched_barrier(0);
  __builtin_amdgcn_s_barrier();

  for (int kt = 0; kt < NT; ++kt){
    const int cur = kt & 1, nxt = cur ^ 1;
    const unsigned short* Ah = &lds[cur][wm][0];
    const unsigned short* Bh = &lds[cur][2 + (wn>>1)][0];
    const int rbase = (wn & 1) * 64;

    // ================= phase 0: n-half 0 =================
    bf16x8 Ar[8][2];
    #pragma unroll
    for (int fm=0;fm<8;++fm)
      #pragma unroll
      for (int ks=0;ks<2;++ks)
        Ar[fm][ks] = frag(Ah, fm*16 + (lane&15), ks*4 + hi);
    bf16x8 b00 = frag(Bh, rbase + (lane&15),      0*4 + hi);
    bf16x8 b01 = frag(Bh, rbase + (lane&15),      1*4 + hi);
    bf16x8 b10 = frag(Bh, rbase + 16 + (lane&15), 0*4 + hi);
    bf16x8 b11 = frag(Bh, rbase + 16 + (lane&15), 1*4 + hi);

    if (kt+1 < NT){
      stage(Bw, n0,     (kt+1)*64, nxt, 2);
      stage(Bw, n0+128, (kt+1)*64, nxt, 3);
    }
    __builtin_amdgcn_sched_barrier(0);
    __builtin_amdgcn_s_barrier();

    __builtin_amdgcn_s_setprio(1);
    #pragma unroll
    for (int fm=0;fm<8;++fm){
      acc[fm][0] = __builtin_amdgcn_mfma_f32_16x16x32_bf16(Ar[fm][0], b00, acc[fm][0], 0,0,0);
      acc[fm][0] = __builtin_amdgcn_mfma_f32_16x16x32_bf16(Ar[fm][1], b01, acc[fm][0], 0,0,0);
      acc[fm][1] = __builtin_amdgcn_mfma_f32_16x16x32_bf16(Ar[fm][0], b10, acc[fm][1], 0,0,0);
      acc[fm][1] = __builtin_amdgcn_mfma_f32_16x16x32_bf16(Ar[fm][1], b11, acc[fm][1], 0,0,0);
    }
    __builtin_amdgcn_s_setprio(0);
    __builtin_amdgcn_sched_barrier(0);
    __builtin_amdgcn_s_barrier();

    // ================= phase 1: n-half 1 =================
    bf16x8 b20 = frag(Bh, rbase + 32 + (lane&15), 0*4 + hi);
    bf16x8 b21 = frag(Bh, rbase + 32 + (lane&15), 1*4 + hi);
    bf16x8 b30 = frag(Bh, rbase + 48 + (lane&15), 0*4 + hi);
    bf16x8 b31 = frag(Bh, rbase + 48 + (lane&15), 1*4 + hi);

    if (kt+2 < NT){
      stage(A, m0,     (kt+2)*64, cur, 0);
      stage(A, m0+128, (kt+2)*64, cur, 1);
    }
    __builtin_amdgcn_sched_barrier(0);
    __builtin_amdgcn_s_barrier();

    __builtin_amdgcn_s_setprio(1);
    #pragma unroll
    for (int fm=0;fm<8;++fm){
      acc[fm][2] = __builtin_amdgcn_mfma_f32_16x16x32_bf16(Ar[fm][0], b20, acc[fm][2], 0,0,0);
      acc[fm][2] = __builtin_amdgcn_mfma_f32_16x16x32_bf16(Ar[fm][1], b21, acc[fm][2], 0,0,0);
      acc[fm][3] = __builtin_amdgcn_mfma_f32_16x16x32_bf16(Ar[fm][0], b30, acc[fm][3], 0,0,0);
      acc[fm][3] = __builtin_amdgcn_mfma_f32_16x16x32_bf16(Ar[fm][1], b31, acc[fm][3], 0,0,0);
    }
    __builtin_amdgcn_s_setprio(0);

    if (kt+2 < NT)      asm volatile("s_waitcnt vmcnt(4)" ::: "memory");
    else if (kt+1 < NT) asm volatile("s_waitcnt vmcnt(0)" ::: "memory");
    __builtin_amdgcn_sched_barrier(0);
    __builtin_amdgcn_s_barrier();
  }

  // ---- epilogue ----
  if (MODE == 0 && (n0 >> 11) == 2){
    // V block: transpose 256x256 tile through LDS, store vT rows coalesced.
    __builtin_amdgcn_s_barrier();                 // K-loop LDS reads all done
    unsigned short* trsp = smem;                  // [256 d][264] ushorts
    #pragma unroll
    for (int fm=0;fm<8;++fm){
      const int srow = wm*128 + fm*16 + hi*4;     // local s base (4 rows)
      #pragma unroll
      for (int p=0;p<4;++p){
        const int dcol = wn*64 + p*16 + (lane&15);
        f32x4 v = acc[fm][p];
        ushort4 pk;
        pk.x=f2bf(v[0]); pk.y=f2bf(v[1]); pk.z=f2bf(v[2]); pk.w=f2bf(v[3]);
        *reinterpret_cast<ushort4*>(trsp + dcol*264 + srow) = pk;
      }
    }
    __syncthreads();
    const int bb  = m0 >> 11;
    const int ss0 = m0 & 2047;
    const size_t vrow = (size_t)(bb*2048 + (n0 - 4096));
    const int t = threadIdx.x;
    #pragma unroll
    for (int it=0; it<16; ++it){
      const int dl = it*16 + (t>>5);
      const int ch = t & 31;
      ushort8v val = *reinterpret_cast<const ushort8v*>(trsp + dl*264 + ch*8);
      *reinterpret_cast<ushort8v*>(vo + (vrow + dl)*SEQ + ss0 + ch*8) = val;
    }
  } else {
    #pragma unroll
    for (int fm=0;fm<8;++fm){
      const int row0 = m0 + wm*128 + fm*16 + (hi<<2);
      #pragma unroll
      for (int p=0;p<4;++p){
        const int col = n0 + wn*64 + p*16 + (lane & 15);
        f32x4 v = acc[fm][p];
        if (MODE == 1){
          #pragma unroll
          for (int r=0;r<4;++r) Cf[(size_t)(row0+r)*N + col] = v[r];
        } else {
          const int part = col >> 11;       // 0=q 1=k (v handled above)
          const int hh = (col >> 7) & 15;
          const int d  = col & 127;
          const int bb = row0 >> 11;
          const int ss = row0 & 2047;
          unsigned short* base = (part == 0 ? qo : ko)
                               + ((size_t)(bb*NHEADS+hh)*SEQ + ss)*HDIM + d;
          #pragma unroll
          for (int r=0;r<4;++r) base[r*HDIM] = f2bf(v[r]);
        }
      }
    }
  }
}

// ---------------- m97-style 128x128 B^T GEMM (out-proj) --------------------
template<int MODE>
__global__ __launch_bounds__(256) void gemm_bt(
    const unsigned short* __restrict__ A,
    const unsigned short* __restrict__ Bw,
    float* __restrict__ Cf,
    int M, int N, int K)
{
  __shared__ __align__(16) unsigned short As[128*32];
  __shared__ __align__(16) unsigned short Bs[128*32];
  const int lane = threadIdx.x & 63;
  const int wid  = threadIdx.x >> 6;
  const int m0 = blockIdx.y * 128;
  const int n0 = blockIdx.x * 128;
  const int wr = wid >> 1, wc = wid & 1;

  f32x4 acc[4][4];
  #pragma unroll
  for (int i=0;i<4;++i)
    #pragma unroll
    for (int j=0;j<4;++j) acc[i][j] = (f32x4){0.f,0.f,0.f,0.f};

  const int sr  = lane >> 2;
  const int scb = (lane & 3) << 4;

  for (int kt = 0; kt < (K >> 5); ++kt){
    const int k0 = kt << 5;
    __syncthreads();
    #pragma unroll
    for (int i=0;i<2;++i){
      const int rloc = ((wid<<1)+i)*16 + sr;
      const int cb = scb ^ ((rloc & 3) << 4);
      gload_lds16(A  + (size_t)(m0+rloc)*K + k0 + (cb>>1), As + ((wid<<1)+i)*512);
      gload_lds16(Bw + (size_t)(n0+rloc)*K + k0 + (cb>>1), Bs + ((wid<<1)+i)*512);
    }
    __syncthreads();

    bf16x8 af[4], bfv[4];
    #pragma unroll
    for (int t=0;t<4;++t){
      const int ra = wr*64 + t*16 + (lane & 15);
      const int ca = (((lane>>4)<<4) ^ ((ra&3)<<4)) >> 1;
      af[t]  = *reinterpret_cast<const bf16x8*>(As + ra*32 + ca);
      const int rbq = wc*64 + t*16 + (lane & 15);
      const int cbb = (((lane>>4)<<4) ^ ((rbq&3)<<4)) >> 1;
      bfv[t] = *reinterpret_cast<const bf16x8*>(Bs + rbq*32 + cbb);
    }
    #pragma unroll
    for (int i=0;i<4;++i)
      #pragma unroll
      for (int j=0;j<4;++j)
        acc[i][j] = __builtin_amdgcn_mfma_f32_16x16x32_bf16(af[i], bfv[j], acc[i][j], 0,0,0);
  }

  #pragma unroll
  for (int i=0;i<4;++i){
    const int row0 = m0 + wr*64 + i*16 + ((lane>>4)<<2);
    #pragma unroll
    for (int j=0;j<4;++j){
      const int col = n0 + wc*64 + j*16 + (lane & 15);
      f32x4 v = acc[i][j];
      #pragma unroll
      for (int r=0;r<4;++r) Cf[(size_t)(row0+r)*N + col] = v[r];
    }
  }
}

// ---------------- RoPE in-place on q,k -------------------------------------
__global__ void rope_kernel(unsigned short* __restrict__ qh, unsigned short* __restrict__ kh){
  const int idx = blockIdx.x * blockDim.x + threadIdx.x; // j(6)|s(11)|bh(5)|t(1)
  const int j  = idx & 63;
  const int s  = (idx >> 6) & 2047;
  const int bh = (idx >> 17) & 31;
  const int t  = idx >> 22;
  unsigned short* base = (t ? kh : qh) + ((size_t)bh*SEQ + s)*HDIM;
  const float x1 = bf2f(base[j]);
  const float x2 = bf2f(base[j+64]);
  const float inv = exp2f(-(float)j * (13.287712379549449f/64.f));
  const float ang = (float)s * inv;
  float sn, cs;
  sincosf(ang, &sn, &cs);
  float o1 = x1*cs - x2*sn;
  float o2 = x2*cs + x1*sn;
  const float QSCALE = 0.08838834764831845f * 1.4426950408889634f;
  if (t == 0){ o1 *= QSCALE; o2 *= QSCALE; }
  base[j]    = f2bf(o1);
  base[j+64] = f2bf(o2);
}

// ---------------- causal flash attention (v3, unchanged) -------------------
__global__ __launch_bounds__(256, 2) void attn_kernel(
    const unsigned short* __restrict__ qh,
    const unsigned short* __restrict__ kh,
    const unsigned short* __restrict__ vT,
    unsigned short* __restrict__ ao)
{
  __shared__ __align__(16) unsigned short Ks[2][64*128];
  __shared__ __align__(16) unsigned short Vs[2][128*64];
  __shared__ __align__(16) unsigned short Ps[4][16*64];

  const int lane = threadIdx.x & 63;
  const int wid  = threadIdx.x >> 6;
  const int hi   = lane >> 4;
  const int pr = blockIdx.x;
  const int bh = blockIdx.y;
  const int b_ = bh >> 4, h_ = bh & 15;

  const unsigned short* Qb = qh + (size_t)bh * SEQ * HDIM;
  const unsigned short* Kb = kh + (size_t)bh * SEQ * HDIM;
  const unsigned short* Vb = vT + (size_t)bh * HDIM * SEQ;

  auto stageKV = [&](int kg, int buf){
    #pragma unroll
    for (int i=0;i<4;++i){
      const int r  = (wid*4+i)*4 + (lane>>4);
      const int cb = ((lane&15)<<4) ^ ((r&7)<<4);
      gload_lds16(Kb + (size_t)(kg*64 + r)*HDIM + (cb>>1), &Ks[buf][0] + (wid*4+i)*512);
    }
    #pragma unroll
    for (int i=0;i<4;++i){
      const int d  = (wid*4+i)*8 + (lane>>3);
      const int cb = ((lane&7)<<4) ^ ((d&7)<<4);
      gload_lds16(Vb + (size_t)d*SEQ + kg*64 + (cb>>1), &Vs[buf][0] + (wid*4+i)*512);
    }
  };

  for (int ph = 0; ph < 2; ++ph){
    const int qt = ph ? (31 - pr) : pr;
    const int qrow0w = qt*QBLK + wid*16;

    bf16x8 qf[4];
    {
      const int qr = qrow0w + (lane & 15);
      #pragma unroll
      for (int ks = 0; ks < 4; ++ks)
        qf[ks] = *reinterpret_cast<const bf16x8*>(Qb + (size_t)qr*HDIM + ks*32 + hi*8);
    }

    f32x4 oacc[8];
    #pragma unroll
    for (int t=0;t<8;++t) oacc[t] = (f32x4){0.f,0.f,0.f,0.f};
    float mrun[4] = {-3.0e38f,-3.0e38f,-3.0e38f,-3.0e38f};
    float lrun[4] = {0.f,0.f,0.f,0.f};

    const int nkt = qt + 1;

    stageKV(0, 0);
    __syncthreads();

    for (int kt = 0; kt < nkt; ++kt){
      const int cur = kt & 1;
      if (kt + 1 < nkt) stageKV(kt + 1, cur ^ 1);

      if (kt*64 <= qrow0w + 15){
        f32x4 sacc[4];
        #pragma unroll
        for (int nt=0;nt<4;++nt) sacc[nt] = (f32x4){0.f,0.f,0.f,0.f};
        __builtin_amdgcn_s_setprio(1);
        #pragma unroll
        for (int nt=0;nt<4;++nt){
          const int krow = nt*16 + (lane&15);
          #pragma unroll
          for (int ks=0;ks<4;++ks){
            const int cb = (ks*64 + (hi<<4)) ^ ((krow&7)<<4);
            bf16x8 kf = *reinterpret_cast<const bf16x8*>(&Ks[cur][0] + krow*128 + (cb>>1));
            sacc[nt] = __builtin_amdgcn_mfma_f32_16x16x32_bf16(qf[ks], kf, sacc[nt], 0,0,0);
          }
        }
        __builtin_amdgcn_s_setprio(0);

        if (kt*64 + 63 > qrow0w){
          #pragma unroll
          for (int nt=0;nt<4;++nt){
            const int key = kt*64 + nt*16 + (lane&15);
            #pragma unroll
            for (int r=0;r<4;++r){
              const int qr = qrow0w + hi*4 + r;
              if (key > qr) sacc[nt][r] = -1.0e30f;
            }
          }
        }

        float fac[4];
        #pragma unroll
        for (int r=0;r<4;++r){
          float mx = fmaxf(fmaxf(sacc[0][r], sacc[1][r]),
                           fmaxf(sacc[2][r], sacc[3][r]));
          mx = rmax16(mx);
          const float mnew = fmaxf(mrun[r], mx);
          fac[r] = exp2f(mrun[r] - mnew);
          mrun[r] = mnew;
          float ps = 0.f;
          #pragma unroll
          for (int nt=0;nt<4;++nt){
            const float p = exp2f(sacc[nt][r] - mnew);
            sacc[nt][r] = p;
            ps += p;
          }
          ps = rsum16(ps);
          lrun[r] = lrun[r]*fac[r] + ps;
        }
        #pragma unroll
        for (int t=0;t<8;++t)
          #pragma unroll
          for (int r=0;r<4;++r) oacc[t][r] *= fac[r];

        char* pb = (char*)&Ps[wid][0];
        #pragma unroll
        for (int nt=0;nt<4;++nt){
          const int keyb = (nt*16 + (lane&15)) << 1;
          #pragma unroll
          for (int r=0;r<4;++r){
            const int prow = hi*4 + r;
            *(unsigned short*)(pb + prow*128 + (keyb ^ ((prow&7)<<4))) = f2bf(sacc[nt][r]);
          }
        }
        asm volatile("s_waitcnt lgkmcnt(0)" ::: "memory");
        __builtin_amdgcn_sched_barrier(0);

        bf16x8 pa[2];
        {
          const int prow = lane & 15;
          #pragma unroll
          for (int ks=0;ks<2;++ks){
            const int pcb = (ks*64 + (hi<<4)) ^ ((prow&7)<<4);
            pa[ks] = *reinterpret_cast<const bf16x8*>(pb + prow*128 + pcb);
          }
        }
        __builtin_amdgcn_s_setprio(1);
        #pragma unroll
        for (int ks=0;ks<2;++ks){
          #pragma unroll
          for (int t=0;t<8;++t){
            const int drow = t*16 + (lane&15);
            const int vcb = (ks*64 + (hi<<4)) ^ ((drow&7)<<4);
            bf16x8 vb = *reinterpret_cast<const bf16x8*>(&Vs[cur][0] + drow*64 + (vcb>>1));
            oacc[t] = __builtin_amdgcn_mfma_f32_16x16x32_bf16(pa[ks], vb, oacc[t], 0,0,0);
          }
        }
        __builtin_amdgcn_s_setprio(0);
      }

      __syncthreads();
    }

    float linv[4];
    #pragma unroll
    for (int r=0;r<4;++r) linv[r] = 1.0f / lrun[r];
    #pragma unroll
    for (int t=0;t<8;++t){
      const int col = h_*HDIM + t*16 + (lane&15);
      #pragma unroll
      for (int r=0;r<4;++r){
        const int s_ = qrow0w + hi*4 + r;
        ao[(size_t)(b_*SEQ + s_)*DMODEL + col] = f2bf(oacc[t][r] * linv[r]);
      }
    }
  }
}

// ---------------- launch ----------------
extern "C" void kernel_launch(void* const* d_in, const int* in_sizes, int n_in,
                              void* d_out, int out_size, void* d_ws, size_t ws_size,
                              hipStream_t stream)
{
  const float* x     = (const float*)d_in[0];
  const float* w_qkv = (const float*)d_in[1];
  const float* w_out = (const float*)d_in[2];
  float* out = (float*)d_out;

  unsigned short* xb    = (unsigned short*)d_ws;                 // 4096x2048
  unsigned short* wqkvb = xb    + (size_t)MTOT*DMODEL;           // 6144x2048
  unsigned short* woutb = wqkvb + (size_t)NQKV*DMODEL;           // 2048x2048
  unsigned short* qhb   = woutb + (size_t)DMODEL*DMODEL;         // (B,H,S,D)
  unsigned short* khb   = qhb   + (size_t)MTOT*DMODEL;           // (B,H,S,D)
  unsigned short* vtb   = khb   + (size_t)MTOT*DMODEL;           // (B,H,D,S)
  unsigned short* aob   = vtb   + (size_t)MTOT*DMODEL;           // 4096x2048

  hipLaunchKernelGGL(cast3_kernel, dim3(1024), dim3(256), 0, stream,
                     x, xb, MTOT*DMODEL, w_qkv, wqkvb, NQKV*DMODEL, w_out, woutb, DMODEL*DMODEL);
  hipLaunchKernelGGL((gemm8<0>), dim3(NQKV/256, MTOT/256), dim3(512), 0, stream,
                     xb, wqkvb, (float*)nullptr, qhb, khb, vtb, MTOT, NQKV, DMODEL);
  hipLaunchKernelGGL(rope_kernel, dim3((2*BATCH*NHEADS*SEQ*64)/256), dim3(256), 0, stream, qhb, khb);
  hipLaunchKernelGGL(attn_kernel, dim3(16, BATCH*NHEADS), dim3(256), 0, stream, qhb, khb, vtb, aob);
  hipLaunchKernelGGL((gemm_bt<1>), dim3(DMODEL/128, MTOT/128), dim3(256), 0, stream,
                     aob, woutb, out, MTOT, DMODEL, DMODEL);
}

// Round 7
// 295.020 us; speedup vs baseline: 1.9574x; 1.0212x over previous
//
#include <hip/hip_runtime.h>
#include <cstdint>
#include <cstddef>

#define NHEADS 16
#define HDIM   128
#define BATCH  2
#define SEQ    2048
#define DMODEL 2048
#define MTOT   (BATCH*SEQ)     // 4096
#define NQKV   (3*DMODEL)      // 6144
#define QBLK   64              // attn: per-block q-rows per half (4 waves x 16)

typedef __attribute__((ext_vector_type(8))) __bf16 bf16x8;
typedef __attribute__((ext_vector_type(4))) float f32x4;
typedef __attribute__((ext_vector_type(8))) unsigned short ushort8v;

__device__ __forceinline__ unsigned short f2bf(float f){
  __bf16 h = (__bf16)f;
  return __builtin_bit_cast(unsigned short, h);
}
__device__ __forceinline__ float bf2f(unsigned short s){
  return __uint_as_float(((uint32_t)s) << 16);
}
// async global->LDS, 16B per lane; LDS dest is wave-uniform base (+lane*16 by HW)
__device__ __forceinline__ void gload_lds16(const void* src, void* lds_base){
  __builtin_amdgcn_global_load_lds((const __attribute__((address_space(1))) unsigned int*)src,
                                   (__attribute__((address_space(3))) unsigned int*)lds_base,
                                   16, 0, 0);
}

// DPP 16-lane-row rotation butterflies (see round 2)
template<int CTRL>
__device__ __forceinline__ float dppmv(float x){
  return __uint_as_float((unsigned)__builtin_amdgcn_update_dpp(
      0, (int)__float_as_uint(x), CTRL, 0xF, 0xF, true));
}
__device__ __forceinline__ float rmax16(float x){
  x = fmaxf(x, dppmv<0x128>(x));
  x = fmaxf(x, dppmv<0x124>(x));
  x = fmaxf(x, dppmv<0x122>(x));
  x = fmaxf(x, dppmv<0x121>(x));
  return x;
}
__device__ __forceinline__ float rsum16(float x){
  x += dppmv<0x128>(x);
  x += dppmv<0x124>(x);
  x += dppmv<0x122>(x);
  x += dppmv<0x121>(x);
  return x;
}

// ---------------- fused cast fp32 -> bf16 (3 arrays, 1 launch) -------------
__global__ void cast3_kernel(const float* __restrict__ s0, unsigned short* __restrict__ d0, int n0,
                             const float* __restrict__ s1, unsigned short* __restrict__ d1, int n1,
                             const float* __restrict__ s2, unsigned short* __restrict__ d2, int n2){
  const int stride = gridDim.x*blockDim.x*8;
  const int base = (blockIdx.x*blockDim.x + threadIdx.x)*8;
  #pragma unroll 1
  for (int a = 0; a < 3; ++a){
    const float* s = a==0 ? s0 : (a==1 ? s1 : s2);
    unsigned short* d = a==0 ? d0 : (a==1 ? d1 : d2);
    const int n = a==0 ? n0 : (a==1 ? n1 : n2);
    for (int i = base; i < n; i += stride){
      float4 x = *reinterpret_cast<const float4*>(s + i);
      float4 y = *reinterpret_cast<const float4*>(s + i + 4);
      ushort8v o;
      o[0]=f2bf(x.x); o[1]=f2bf(x.y); o[2]=f2bf(x.z); o[3]=f2bf(x.w);
      o[4]=f2bf(y.x); o[5]=f2bf(y.y); o[6]=f2bf(y.z); o[7]=f2bf(y.w);
      *reinterpret_cast<ushort8v*>(d + i) = o;
    }
  }
}

// ---------------- 256x256 B^T GEMM, BK=64, 4-phase counted-vmcnt -----------
// C[m,n] = sum_k A[m,k]*Bw[n,k]. 8 waves (2M x 4N), per-wave out 128x64.
// LDS: 2 buf x 4 half-tiles {A0,A1,B0,B1} x [128][64] bf16 = 128 KiB.
// Slot last-read table (within tile t): A0:P2, A1:P2, B0:P1, B1:P1.
// Stage calendar (RACE-FIXED r7: a cur-slot stage must issue in a phase
// STRICTLY AFTER the slot's last-read phase -- r6 staged A0 at P1 and
// corrupted rows 64-127 read at P2):
//   P0: rd A-h0(8)+B-h0(4);  stage t+1.B1 -> nxt        MFMA m0n0
//   P1: rd B-h1(4);          (no stage)                 MFMA m0n1
//   P2: rd A-h1(8);          stage t+2.B0 -> cur        MFMA m1n0
//   P3: (no reads);          stage t+2.A0,A1 -> cur     MFMA m1n1; vmcnt(6)
// FIFO at P3 wait: 7 stages (14 loads) out -> vmcnt(6) retires 4 oldest =
// tile t+1 fully landed; {t+2.B0,A0,A1} (6 loads) stay in flight.
template<int MODE>
__global__ __launch_bounds__(512, 2) void gemm8(
    const unsigned short* __restrict__ A,
    const unsigned short* __restrict__ Bw,
    float* __restrict__ Cf,
    unsigned short* __restrict__ qo,
    unsigned short* __restrict__ ko,
    unsigned short* __restrict__ vo,
    int M, int N, int K)
{
  // 135168 B: staging view needs 131072; V-transpose view needs 256*264*2
  __shared__ __align__(16) unsigned short smem[256*264];
  auto lds = reinterpret_cast<unsigned short (*)[4][128*64]>(smem);  // [2][4][8192]
  // half-tile slots: 0=A0 1=A1 2=B0 3=B1

  const int lane = threadIdx.x & 63;
  const int wid  = threadIdx.x >> 6;
  const int wm = wid >> 2, wn = wid & 3;
  const int hi = lane >> 4;

  // bijective XCD swizzle (grid size 384, multiple of 8)
  const int nwg = gridDim.x * gridDim.y;
  const int bid = blockIdx.y * gridDim.x + blockIdx.x;
  const int swz = (bid & 7) * (nwg >> 3) + (bid >> 3);
  const int by = swz & (gridDim.y - 1);          // gridDim.y = 16 (pow2)
  const int bx = swz >> 4;
  const int m0 = by * 256;
  const int n0 = bx * 256;

  const int NT = K >> 6;

  auto stage = [&](const unsigned short* base, int row0, int k0, int buf, int ht){
    const int rlo = wid << 4;
    #pragma unroll
    for (int i=0;i<2;++i){
      const int r = rlo + i*8 + (lane>>3);
      const int csrc = ((lane&7) ^ (lane>>3)) << 3;   // elems
      gload_lds16(base + (size_t)(row0 + r)*K + k0 + csrc,
                  &lds[buf][ht][(rlo + i*8)*64]);
    }
  };
  auto frag = [&](const unsigned short* h, int r, int s){
    return *reinterpret_cast<const bf16x8*>(h + r*64 + ((s ^ (r&7)) << 3));
  };

  f32x4 acc[8][4];
  #pragma unroll
  for (int i=0;i<8;++i)
    #pragma unroll
    for (int j=0;j<4;++j) acc[i][j] = (f32x4){0.f,0.f,0.f,0.f};

  // ---- prologue: t0 {A0,B0,A1,B1} + t1 {B0,A0,A1}; vmcnt(6) => t0 landed,
  //      3 half-tiles of t1 (6 loads) in flight — steady-state entry.
  stage(A,  m0,      0, 0, 0);
  stage(Bw, n0,      0, 0, 2);
  stage(A,  m0+128,  0, 0, 1);
  stage(Bw, n0+128,  0, 0, 3);
  if (NT > 1){
    stage(Bw, n0,     64, 1, 2);
    stage(A,  m0,     64, 1, 0);
    stage(A,  m0+128, 64, 1, 1);
    asm volatile("s_waitcnt vmcnt(6)" ::: "memory");
  } else {
    asm volatile("s_waitcnt vmcnt(0)" ::: "memory");
  }
  __builtin_amdgcn_sched_barrier(0);
  __builtin_amdgcn_s_barrier();

  bf16x8 Ar[4][2];          // current m-half frags
  bf16x8 Br0[2][2], Br1[2][2];

  auto tile_body = [&](int kt, int cur){
    const int nxt = cur ^ 1;
    const unsigned short* Ah0 = &lds[cur][wm][0];         // wave's A slot (128 rows)
    const unsigned short* Bh  = &lds[cur][2 + (wn>>1)][0];
    const int rbase = (wn & 1) * 64;
    const int l15 = lane & 15;

    // ================= P0: A-h0 + B-h0 reads; stage t+1.B1 -> nxt ==========
    #pragma unroll
    for (int fm=0;fm<4;++fm)
      #pragma unroll
      for (int kk=0;kk<2;++kk)
        Ar[fm][kk] = frag(Ah0, fm*16 + l15, kk*4 + hi);
    #pragma unroll
    for (int nf=0;nf<2;++nf)
      #pragma unroll
      for (int kk=0;kk<2;++kk)
        Br0[nf][kk] = frag(Bh, rbase + nf*16 + l15, kk*4 + hi);
    if (kt+1 < NT) stage(Bw, n0+128, (kt+1)*64, nxt, 3);
    asm volatile("s_waitcnt lgkmcnt(8)" ::: "memory");
    __builtin_amdgcn_sched_barrier(0);
    __builtin_amdgcn_s_barrier();
    asm volatile("s_waitcnt lgkmcnt(0)" ::: "memory");
    __builtin_amdgcn_sched_barrier(0);
    __builtin_amdgcn_s_setprio(1);
    #pragma unroll
    for (int fm=0;fm<4;++fm)
      #pragma unroll
      for (int nf=0;nf<2;++nf){
        acc[fm][nf] = __builtin_amdgcn_mfma_f32_16x16x32_bf16(Ar[fm][0], Br0[nf][0], acc[fm][nf], 0,0,0);
        acc[fm][nf] = __builtin_amdgcn_mfma_f32_16x16x32_bf16(Ar[fm][1], Br0[nf][1], acc[fm][nf], 0,0,0);
      }
    __builtin_amdgcn_s_setprio(0);
    __builtin_amdgcn_sched_barrier(0);
    __builtin_amdgcn_s_barrier();

    // ================= P1: B-h1 reads; no stage ============================
    #pragma unroll
    for (int nf=0;nf<2;++nf)
      #pragma unroll
      for (int kk=0;kk<2;++kk)
        Br1[nf][kk] = frag(Bh, rbase + 32 + nf*16 + l15, kk*4 + hi);
    __builtin_amdgcn_sched_barrier(0);
    __builtin_amdgcn_s_barrier();
    asm volatile("s_waitcnt lgkmcnt(0)" ::: "memory");
    __builtin_amdgcn_sched_barrier(0);
    __builtin_amdgcn_s_setprio(1);
    #pragma unroll
    for (int fm=0;fm<4;++fm)
      #pragma unroll
      for (int nf=0;nf<2;++nf){
        acc[fm][2+nf] = __builtin_amdgcn_mfma_f32_16x16x32_bf16(Ar[fm][0], Br1[nf][0], acc[fm][2+nf], 0,0,0);
        acc[fm][2+nf] = __builtin_amdgcn_mfma_f32_16x16x32_bf16(Ar[fm][1], Br1[nf][1], acc[fm][2+nf], 0,0,0);
      }
    __builtin_amdgcn_s_setprio(0);
    __builtin_amdgcn_sched_barrier(0);
    __builtin_amdgcn_s_barrier();

    // ================= P2: A-h1 reads; stage t+2.B0 -> cur =================
    // (cur.B0 last read at P1, drained by P1's lgkmcnt(0) + barrier)
    #pragma unroll
    for (int fm=0;fm<4;++fm)
      #pragma unroll
      for (int kk=0;kk<2;++kk)
        Ar[fm][kk] = frag(Ah0, 64 + fm*16 + l15, kk*4 + hi);
    if (kt+2 < NT) stage(Bw, n0, (kt+2)*64, cur, 2);
    __builtin_amdgcn_sched_barrier(0);
    __builtin_amdgcn_s_barrier();
    asm volatile("s_waitcnt lgkmcnt(0)" ::: "memory");
    __builtin_amdgcn_sched_barrier(0);
    __builtin_amdgcn_s_setprio(1);
    #pragma unroll
    for (int fm=0;fm<4;++fm)
      #pragma unroll
      for (int nf=0;nf<2;++nf){
        acc[4+fm][nf] = __builtin_amdgcn_mfma_f32_16x16x32_bf16(Ar[fm][0], Br0[nf][0], acc[4+fm][nf], 0,0,0);
        acc[4+fm][nf] = __builtin_amdgcn_mfma_f32_16x16x32_bf16(Ar[fm][1], Br0[nf][1], acc[4+fm][nf], 0,0,0);
      }
    __builtin_amdgcn_s_setprio(0);
    __builtin_amdgcn_sched_barrier(0);
    __builtin_amdgcn_s_barrier();

    // ================= P3: stage t+2.A0,A1 -> cur; MFMA; vmcnt(6) ==========
    // (cur.A0/A1 last read at P2, drained by P2's lgkmcnt(0) + barrier)
    if (kt+2 < NT){
      stage(A, m0,     (kt+2)*64, cur, 0);
      stage(A, m0+128, (kt+2)*64, cur, 1);
    }
    __builtin_amdgcn_sched_barrier(0);
    __builtin_amdgcn_s_setprio(1);
    #pragma unroll
    for (int fm=0;fm<4;++fm)
      #pragma unroll
      for (int nf=0;nf<2;++nf){
        acc[4+fm][2+nf] = __builtin_amdgcn_mfma_f32_16x16x32_bf16(Ar[fm][0], Br1[nf][0], acc[4+fm][2+nf], 0,0,0);
        acc[4+fm][2+nf] = __builtin_amdgcn_mfma_f32_16x16x32_bf16(Ar[fm][1], Br1[nf][1], acc[4+fm][2+nf], 0,0,0);
      }
    __builtin_amdgcn_s_setprio(0);
    if (kt+2 < NT)      asm volatile("s_waitcnt vmcnt(6)" ::: "memory");
    else if (kt+1 < NT) asm volatile("s_waitcnt vmcnt(0)" ::: "memory");
    __builtin_amdgcn_sched_barrier(0);
    __builtin_amdgcn_s_barrier();
  };

  for (int kt2 = 0; kt2 < NT; kt2 += 2){
    tile_body(kt2,     0);
    tile_body(kt2 + 1, 1);
  }

  // ---- epilogue ----
  if (MODE == 0 && (n0 >> 11) == 2){
    // V block: transpose 256x256 tile through LDS, store vT rows coalesced.
    __builtin_amdgcn_s_barrier();                 // K-loop LDS reads all done
    unsigned short* trsp = smem;                  // [256 d][264] ushorts
    #pragma unroll
    for (int fm=0;fm<8;++fm){
      const int srow = wm*128 + fm*16 + hi*4;     // local s base (4 rows)
      #pragma unroll
      for (int p=0;p<4;++p){
        const int dcol = wn*64 + p*16 + (lane&15);
        f32x4 v = acc[fm][p];
        ushort4 pk;
        pk.x=f2bf(v[0]); pk.y=f2bf(v[1]); pk.z=f2bf(v[2]); pk.w=f2bf(v[3]);
        *reinterpret_cast<ushort4*>(trsp + dcol*264 + srow) = pk;
      }
    }
    __syncthreads();
    const int bb  = m0 >> 11;
    const int ss0 = m0 & 2047;
    const size_t vrow = (size_t)(bb*2048 + (n0 - 4096));
    const int t = threadIdx.x;
    #pragma unroll
    for (int it=0; it<16; ++it){
      const int dl = it*16 + (t>>5);
      const int ch = t & 31;
      ushort8v val = *reinterpret_cast<const ushort8v*>(trsp + dl*264 + ch*8);
      *reinterpret_cast<ushort8v*>(vo + (vrow + dl)*SEQ + ss0 + ch*8) = val;
    }
  } else {
    #pragma unroll
    for (int fm=0;fm<8;++fm){
      const int row0 = m0 + wm*128 + fm*16 + (hi<<2);
      #pragma unroll
      for (int p=0;p<4;++p){
        const int col = n0 + wn*64 + p*16 + (lane & 15);
        f32x4 v = acc[fm][p];
        if (MODE == 1){
          #pragma unroll
          for (int r=0;r<4;++r) Cf[(size_t)(row0+r)*N + col] = v[r];
        } else {
          const int part = col >> 11;       // 0=q 1=k (v handled above)
          const int hh = (col >> 7) & 15;
          const int d  = col & 127;
          const int bb = row0 >> 11;
          const int ss = row0 & 2047;
          unsigned short* base = (part == 0 ? qo : ko)
                               + ((size_t)(bb*NHEADS+hh)*SEQ + ss)*HDIM + d;
          #pragma unroll
          for (int r=0;r<4;++r) base[r*HDIM] = f2bf(v[r]);
        }
      }
    }
  }
}

// ---------------- m97-style 128x128 B^T GEMM (out-proj) --------------------
template<int MODE>
__global__ __launch_bounds__(256) void gemm_bt(
    const unsigned short* __restrict__ A,
    const unsigned short* __restrict__ Bw,
    float* __restrict__ Cf,
    int M, int N, int K)
{
  __shared__ __align__(16) unsigned short As[128*32];
  __shared__ __align__(16) unsigned short Bs[128*32];
  const int lane = threadIdx.x & 63;
  const int wid  = threadIdx.x >> 6;
  const int m0 = blockIdx.y * 128;
  const int n0 = blockIdx.x * 128;
  const int wr = wid >> 1, wc = wid & 1;

  f32x4 acc[4][4];
  #pragma unroll
  for (int i=0;i<4;++i)
    #pragma unroll
    for (int j=0;j<4;++j) acc[i][j] = (f32x4){0.f,0.f,0.f,0.f};

  const int sr  = lane >> 2;
  const int scb = (lane & 3) << 4;

  for (int kt = 0; kt < (K >> 5); ++kt){
    const int k0 = kt << 5;
    __syncthreads();
    #pragma unroll
    for (int i=0;i<2;++i){
      const int rloc = ((wid<<1)+i)*16 + sr;
      const int cb = scb ^ ((rloc & 3) << 4);
      gload_lds16(A  + (size_t)(m0+rloc)*K + k0 + (cb>>1), As + ((wid<<1)+i)*512);
      gload_lds16(Bw + (size_t)(n0+rloc)*K + k0 + (cb>>1), Bs + ((wid<<1)+i)*512);
    }
    __syncthreads();

    bf16x8 af[4], bfv[4];
    #pragma unroll
    for (int t=0;t<4;++t){
      const int ra = wr*64 + t*16 + (lane & 15);
      const int ca = (((lane>>4)<<4) ^ ((ra&3)<<4)) >> 1;
      af[t]  = *reinterpret_cast<const bf16x8*>(As + ra*32 + ca);
      const int rbq = wc*64 + t*16 + (lane & 15);
      const int cbb = (((lane>>4)<<4) ^ ((rbq&3)<<4)) >> 1;
      bfv[t] = *reinterpret_cast<const bf16x8*>(Bs + rbq*32 + cbb);
    }
    #pragma unroll
    for (int i=0;i<4;++i)
      #pragma unroll
      for (int j=0;j<4;++j)
        acc[i][j] = __builtin_amdgcn_mfma_f32_16x16x32_bf16(af[i], bfv[j], acc[i][j], 0,0,0);
  }

  #pragma unroll
  for (int i=0;i<4;++i){
    const int row0 = m0 + wr*64 + i*16 + ((lane>>4)<<2);
    #pragma unroll
    for (int j=0;j<4;++j){
      const int col = n0 + wc*64 + j*16 + (lane & 15);
      f32x4 v = acc[i][j];
      #pragma unroll
      for (int r=0;r<4;++r) Cf[(size_t)(row0+r)*N + col] = v[r];
    }
  }
}

// ---------------- RoPE in-place on q,k -------------------------------------
__global__ void rope_kernel(unsigned short* __restrict__ qh, unsigned short* __restrict__ kh){
  const int idx = blockIdx.x * blockDim.x + threadIdx.x; // j(6)|s(11)|bh(5)|t(1)
  const int j  = idx & 63;
  const int s  = (idx >> 6) & 2047;
  const int bh = (idx >> 17) & 31;
  const int t  = idx >> 22;
  unsigned short* base = (t ? kh : qh) + ((size_t)bh*SEQ + s)*HDIM;
  const float x1 = bf2f(base[j]);
  const float x2 = bf2f(base[j+64]);
  const float inv = exp2f(-(float)j * (13.287712379549449f/64.f));
  const float ang = (float)s * inv;
  float sn, cs;
  sincosf(ang, &sn, &cs);
  float o1 = x1*cs - x2*sn;
  float o2 = x2*cs + x1*sn;
  const float QSCALE = 0.08838834764831845f * 1.4426950408889634f;
  if (t == 0){ o1 *= QSCALE; o2 *= QSCALE; }
  base[j]    = f2bf(o1);
  base[j+64] = f2bf(o2);
}

// ---------------- causal flash attention (v3, unchanged) -------------------
__global__ __launch_bounds__(256, 2) void attn_kernel(
    const unsigned short* __restrict__ qh,
    const unsigned short* __restrict__ kh,
    const unsigned short* __restrict__ vT,
    unsigned short* __restrict__ ao)
{
  __shared__ __align__(16) unsigned short Ks[2][64*128];
  __shared__ __align__(16) unsigned short Vs[2][128*64];
  __shared__ __align__(16) unsigned short Ps[4][16*64];

  const int lane = threadIdx.x & 63;
  const int wid  = threadIdx.x >> 6;
  const int hi   = lane >> 4;
  const int pr = blockIdx.x;
  const int bh = blockIdx.y;
  const int b_ = bh >> 4, h_ = bh & 15;

  const unsigned short* Qb = qh + (size_t)bh * SEQ * HDIM;
  const unsigned short* Kb = kh + (size_t)bh * SEQ * HDIM;
  const unsigned short* Vb = vT + (size_t)bh * HDIM * SEQ;

  auto stageKV = [&](int kg, int buf){
    #pragma unroll
    for (int i=0;i<4;++i){
      const int r  = (wid*4+i)*4 + (lane>>4);
      const int cb = ((lane&15)<<4) ^ ((r&7)<<4);
      gload_lds16(Kb + (size_t)(kg*64 + r)*HDIM + (cb>>1), &Ks[buf][0] + (wid*4+i)*512);
    }
    #pragma unroll
    for (int i=0;i<4;++i){
      const int d  = (wid*4+i)*8 + (lane>>3);
      const int cb = ((lane&7)<<4) ^ ((d&7)<<4);
      gload_lds16(Vb + (size_t)d*SEQ + kg*64 + (cb>>1), &Vs[buf][0] + (wid*4+i)*512);
    }
  };

  for (int ph = 0; ph < 2; ++ph){
    const int qt = ph ? (31 - pr) : pr;
    const int qrow0w = qt*QBLK + wid*16;

    bf16x8 qf[4];
    {
      const int qr = qrow0w + (lane & 15);
      #pragma unroll
      for (int ks = 0; ks < 4; ++ks)
        qf[ks] = *reinterpret_cast<const bf16x8*>(Qb + (size_t)qr*HDIM + ks*32 + hi*8);
    }

    f32x4 oacc[8];
    #pragma unroll
    for (int t=0;t<8;++t) oacc[t] = (f32x4){0.f,0.f,0.f,0.f};
    float mrun[4] = {-3.0e38f,-3.0e38f,-3.0e38f,-3.0e38f};
    float lrun[4] = {0.f,0.f,0.f,0.f};

    const int nkt = qt + 1;

    stageKV(0, 0);
    __syncthreads();

    for (int kt = 0; kt < nkt; ++kt){
      const int cur = kt & 1;
      if (kt + 1 < nkt) stageKV(kt + 1, cur ^ 1);

      if (kt*64 <= qrow0w + 15){
        f32x4 sacc[4];
        #pragma unroll
        for (int nt=0;nt<4;++nt) sacc[nt] = (f32x4){0.f,0.f,0.f,0.f};
        __builtin_amdgcn_s_setprio(1);
        #pragma unroll
        for (int nt=0;nt<4;++nt){
          const int krow = nt*16 + (lane&15);
          #pragma unroll
          for (int ks=0;ks<4;++ks){
            const int cb = (ks*64 + (hi<<4)) ^ ((krow&7)<<4);
            bf16x8 kf = *reinterpret_cast<const bf16x8*>(&Ks[cur][0] + krow*128 + (cb>>1));
            sacc[nt] = __builtin_amdgcn_mfma_f32_16x16x32_bf16(qf[ks], kf, sacc[nt], 0,0,0);
          }
        }
        __builtin_amdgcn_s_setprio(0);

        if (kt*64 + 63 > qrow0w){
          #pragma unroll
          for (int nt=0;nt<4;++nt){
            const int key = kt*64 + nt*16 + (lane&15);
            #pragma unroll
            for (int r=0;r<4;++r){
              const int qr = qrow0w + hi*4 + r;
              if (key > qr) sacc[nt][r] = -1.0e30f;
            }
          }
        }

        float fac[4];
        #pragma unroll
        for (int r=0;r<4;++r){
          float mx = fmaxf(fmaxf(sacc[0][r], sacc[1][r]),
                           fmaxf(sacc[2][r], sacc[3][r]));
          mx = rmax16(mx);
          const float mnew = fmaxf(mrun[r], mx);
          fac[r] = exp2f(mrun[r] - mnew);
          mrun[r] = mnew;
          float ps = 0.f;
          #pragma unroll
          for (int nt=0;nt<4;++nt){
            const float p = exp2f(sacc[nt][r] - mnew);
            sacc[nt][r] = p;
            ps += p;
          }
          ps = rsum16(ps);
          lrun[r] = lrun[r]*fac[r] + ps;
        }
        #pragma unroll
        for (int t=0;t<8;++t)
          #pragma unroll
          for (int r=0;r<4;++r) oacc[t][r] *= fac[r];

        char* pb = (char*)&Ps[wid][0];
        #pragma unroll
        for (int nt=0;nt<4;++nt){
          const int keyb = (nt*16 + (lane&15)) << 1;
          #pragma unroll
          for (int r=0;r<4;++r){
            const int prow = hi*4 + r;
            *(unsigned short*)(pb + prow*128 + (keyb ^ ((prow&7)<<4))) = f2bf(sacc[nt][r]);
          }
        }
        asm volatile("s_waitcnt lgkmcnt(0)" ::: "memory");
        __builtin_amdgcn_sched_barrier(0);

        bf16x8 pa[2];
        {
          const int prow = lane & 15;
          #pragma unroll
          for (int ks=0;ks<2;++ks){
            const int pcb = (ks*64 + (hi<<4)) ^ ((prow&7)<<4);
            pa[ks] = *reinterpret_cast<const bf16x8*>(pb + prow*128 + pcb);
          }
        }
        __builtin_amdgcn_s_setprio(1);
        #pragma unroll
        for (int ks=0;ks<2;++ks){
          #pragma unroll
          for (int t=0;t<8;++t){
            const int drow = t*16 + (lane&15);
            const int vcb = (ks*64 + (hi<<4)) ^ ((drow&7)<<4);
            bf16x8 vb = *reinterpret_cast<const bf16x8*>(&Vs[cur][0] + drow*64 + (vcb>>1));
            oacc[t] = __builtin_amdgcn_mfma_f32_16x16x32_bf16(pa[ks], vb, oacc[t], 0,0,0);
          }
        }
        __builtin_amdgcn_s_setprio(0);
      }

      __syncthreads();
    }

    float linv[4];
    #pragma unroll
    for (int r=0;r<4;++r) linv[r] = 1.0f / lrun[r];
    #pragma unroll
    for (int t=0;t<8;++t){
      const int col = h_*HDIM + t*16 + (lane&15);
      #pragma unroll
      for (int r=0;r<4;++r){
        const int s_ = qrow0w + hi*4 + r;
        ao[(size_t)(b_*SEQ + s_)*DMODEL + col] = f2bf(oacc[t][r] * linv[r]);
      }
    }
  }
}

// ---------------- launch ----------------
extern "C" void kernel_launch(void* const* d_in, const int* in_sizes, int n_in,
                              void* d_out, int out_size, void* d_ws, size_t ws_size,
                              hipStream_t stream)
{
  const float* x     = (const float*)d_in[0];
  const float* w_qkv = (const float*)d_in[1];
  const float* w_out = (const float*)d_in[2];
  float* out = (float*)d_out;

  unsigned short* xb    = (unsigned short*)d_ws;                 // 4096x2048
  unsigned short* wqkvb = xb    + (size_t)MTOT*DMODEL;           // 6144x2048
  unsigned short* woutb = wqkvb + (size_t)NQKV*DMODEL;           // 2048x2048
  unsigned short* qhb   = woutb + (size_t)DMODEL*DMODEL;         // (B,H,S,D)
  unsigned short* khb   = qhb   + (size_t)MTOT*DMODEL;           // (B,H,S,D)
  unsigned short* vtb   = khb   + (size_t)MTOT*DMODEL;           // (B,H,D,S)
  unsigned short* aob   = vtb   + (size_t)MTOT*DMODEL;           // 4096x2048

  hipLaunchKernelGGL(cast3_kernel, dim3(1024), dim3(256), 0, stream,
                     x, xb, MTOT*DMODEL, w_qkv, wqkvb, NQKV*DMODEL, w_out, woutb, DMODEL*DMODEL);
  hipLaunchKernelGGL((gemm8<0>), dim3(NQKV/256, MTOT/256), dim3(512), 0, stream,
                     xb, wqkvb, (float*)nullptr, qhb, khb, vtb, MTOT, NQKV, DMODEL);
  hipLaunchKernelGGL(rope_kernel, dim3((2*BATCH*NHEADS*SEQ*64)/256), dim3(256), 0, stream, qhb, khb);
  hipLaunchKernelGGL(attn_kernel, dim3(16, BATCH*NHEADS), dim3(256), 0, stream, qhb, khb, vtb, aob);
  hipLaunchKernelGGL((gemm_bt<1>), dim3(DMODEL/128, MTOT/128), dim3(256), 0, stream,
                     aob, woutb, out, MTOT, DMODEL, DMODEL);
}

// Round 8
// 268.654 us; speedup vs baseline: 2.1495x; 1.0981x over previous
//
#include <hip/hip_runtime.h>
#include <cstdint>
#include <cstddef>

#define NHEADS 16
#define HDIM   128
#define BATCH  2
#define SEQ    2048
#define DMODEL 2048
#define MTOT   (BATCH*SEQ)     // 4096
#define NQKV   (3*DMODEL)      // 6144
#define QBLK   64              // attn: per-block q-rows per half (4 waves x 16)

typedef __attribute__((ext_vector_type(8))) __bf16 bf16x8;
typedef __attribute__((ext_vector_type(4))) float f32x4;
typedef __attribute__((ext_vector_type(8))) unsigned short ushort8v;

__device__ __forceinline__ unsigned short f2bf(float f){
  __bf16 h = (__bf16)f;
  return __builtin_bit_cast(unsigned short, h);
}
__device__ __forceinline__ float bf2f(unsigned short s){
  return __uint_as_float(((uint32_t)s) << 16);
}
// async global->LDS, 16B per lane; LDS dest is wave-uniform base (+lane*16 by HW)
__device__ __forceinline__ void gload_lds16(const void* src, void* lds_base){
  __builtin_amdgcn_global_load_lds((const __attribute__((address_space(1))) unsigned int*)src,
                                   (__attribute__((address_space(3))) unsigned int*)lds_base,
                                   16, 0, 0);
}

// DPP 16-lane-row rotation butterflies (see round 2)
template<int CTRL>
__device__ __forceinline__ float dppmv(float x){
  return __uint_as_float((unsigned)__builtin_amdgcn_update_dpp(
      0, (int)__float_as_uint(x), CTRL, 0xF, 0xF, true));
}
__device__ __forceinline__ float rmax16(float x){
  x = fmaxf(x, dppmv<0x128>(x));
  x = fmaxf(x, dppmv<0x124>(x));
  x = fmaxf(x, dppmv<0x122>(x));
  x = fmaxf(x, dppmv<0x121>(x));
  return x;
}
__device__ __forceinline__ float rsum16(float x){
  x += dppmv<0x128>(x);
  x += dppmv<0x124>(x);
  x += dppmv<0x122>(x);
  x += dppmv<0x121>(x);
  return x;
}

// ---------------- fused cast fp32 -> bf16 (3 arrays, 1 launch) -------------
__global__ void cast3_kernel(const float* __restrict__ s0, unsigned short* __restrict__ d0, int n0,
                             const float* __restrict__ s1, unsigned short* __restrict__ d1, int n1,
                             const float* __restrict__ s2, unsigned short* __restrict__ d2, int n2){
  const int stride = gridDim.x*blockDim.x*8;
  const int base = (blockIdx.x*blockDim.x + threadIdx.x)*8;
  #pragma unroll 1
  for (int a = 0; a < 3; ++a){
    const float* s = a==0 ? s0 : (a==1 ? s1 : s2);
    unsigned short* d = a==0 ? d0 : (a==1 ? d1 : d2);
    const int n = a==0 ? n0 : (a==1 ? n1 : n2);
    for (int i = base; i < n; i += stride){
      float4 x = *reinterpret_cast<const float4*>(s + i);
      float4 y = *reinterpret_cast<const float4*>(s + i + 4);
      ushort8v o;
      o[0]=f2bf(x.x); o[1]=f2bf(x.y); o[2]=f2bf(x.z); o[3]=f2bf(x.w);
      o[4]=f2bf(y.x); o[5]=f2bf(y.y); o[6]=f2bf(y.z); o[7]=f2bf(y.w);
      *reinterpret_cast<ushort8v*>(d + i) = o;
    }
  }
}

// ---------- 128x256 B^T GEMM, BK=64, 2-phase counted-vmcnt -----------------
// Tile chosen so tile-count % 256CU == 0 (zero dispatch-tail):
//   QKV:     24x32 = 768 blocks = 3 exact rounds
//   outproj:  8x32 = 256 blocks = 1 exact round
// 8 waves (2M x 4N), per-wave out 64x64 (acc = 64 VGPR).
// LDS: 2 buf x 3 slots {A[128x64], B0[128x64], B1[128x64]} = 96 KiB.
// Slot last-read (tile t): A:P0, B0:P1, B1:P1.
// Calendar (hazard-audited):
//   P0: rd A(8)+B-lo(4); stage t+1.B0,B1 -> nxt  (nxt.B last read t-1 P1)
//       MFMA n-frags 0,1 (16)
//   P1: rd B-hi(4);      stage t+2.A -> cur      (cur.A last read P0)
//       MFMA n-frags 2,3 (16); vmcnt(2)
// FIFO at wait: 8 loads out {A(t+1)[2], B0,B1(t+1)[4], A(t+2)[2]} ->
// vmcnt(2) retires 6 oldest = tile t+1 fully landed; A(t+2) stays in flight.
template<int MODE>
__global__ __launch_bounds__(512, 2) void gemm2(
    const unsigned short* __restrict__ A,
    const unsigned short* __restrict__ Bw,
    float* __restrict__ Cf,
    unsigned short* __restrict__ qo,
    unsigned short* __restrict__ ko,
    unsigned short* __restrict__ vo,
    int M, int N, int K)
{
  // staging view: 2*3*8192 = 49152 ushorts (96 KB); V-transpose view: 256*136
  __shared__ __align__(16) unsigned short smem[49152];
  auto lds = reinterpret_cast<unsigned short (*)[3][128*64]>(smem);  // [2][3][8192]
  // slots: 0=A  1=B0 (n 0..127)  2=B1 (n 128..255)

  const int lane = threadIdx.x & 63;
  const int wid  = threadIdx.x >> 6;
  const int wm = wid >> 2, wn = wid & 3;
  const int hi = lane >> 4;
  const int l15 = lane & 15;

  // bijective XCD swizzle; gridDim.y == 32 (pow2) for both call sites
  const int nwg = gridDim.x * gridDim.y;
  const int bid = blockIdx.y * gridDim.x + blockIdx.x;
  const int swz = (bid & 7) * (nwg >> 3) + (bid >> 3);
  const int by = swz & 31;
  const int bx = swz >> 5;
  const int m0 = by * 128;
  const int n0 = bx * 256;

  const int NT = K >> 6;

  auto stage = [&](const unsigned short* base, int row0, int k0, int buf, int slot){
    const int rlo = wid << 4;
    #pragma unroll
    for (int i=0;i<2;++i){
      const int r = rlo + i*8 + (lane>>3);
      const int csrc = ((lane&7) ^ (lane>>3)) << 3;   // elems
      gload_lds16(base + (size_t)(row0 + r)*K + k0 + csrc,
                  &lds[buf][slot][(rlo + i*8)*64]);
    }
  };
  auto frag = [&](const unsigned short* h, int r, int s){
    return *reinterpret_cast<const bf16x8*>(h + r*64 + ((s ^ (r&7)) << 3));
  };

  f32x4 acc[4][4];
  #pragma unroll
  for (int i=0;i<4;++i)
    #pragma unroll
    for (int j=0;j<4;++j) acc[i][j] = (f32x4){0.f,0.f,0.f,0.f};

  // ---- prologue: t0 {A,B0,B1} + t1 {A}; vmcnt(2) => t0 landed, A(t1) flying
  stage(A,  m0,      0, 0, 0);
  stage(Bw, n0,      0, 0, 1);
  stage(Bw, n0+128,  0, 0, 2);
  if (NT > 1){
    stage(A, m0, 64, 1, 0);
    asm volatile("s_waitcnt vmcnt(2)" ::: "memory");
  } else {
    asm volatile("s_waitcnt vmcnt(0)" ::: "memory");
  }
  __builtin_amdgcn_sched_barrier(0);
  __builtin_amdgcn_s_barrier();

  bf16x8 Ar[4][2];
  bf16x8 Br[2][2];

  auto tile_body = [&](int kt, int cur){
    const int nxt = cur ^ 1;
    const unsigned short* Ah = &lds[cur][0][0];
    const unsigned short* Bh = &lds[cur][1 + (wn>>1)][0];
    const int rbase = (wn & 1) * 64;

    // ===== P0: A(8) + B-lo(4) reads; stage t+1.B0,B1 -> nxt ================
    #pragma unroll
    for (int fm=0;fm<4;++fm)
      #pragma unroll
      for (int kk=0;kk<2;++kk)
        Ar[fm][kk] = frag(Ah, wm*64 + fm*16 + l15, kk*4 + hi);
    #pragma unroll
    for (int nf=0;nf<2;++nf)
      #pragma unroll
      for (int kk=0;kk<2;++kk)
        Br[nf][kk] = frag(Bh, rbase + nf*16 + l15, kk*4 + hi);
    if (kt+1 < NT){
      stage(Bw, n0,     (kt+1)*64, nxt, 1);
      stage(Bw, n0+128, (kt+1)*64, nxt, 2);
    }
    asm volatile("s_waitcnt lgkmcnt(8)" ::: "memory");
    __builtin_amdgcn_sched_barrier(0);
    __builtin_amdgcn_s_barrier();
    asm volatile("s_waitcnt lgkmcnt(0)" ::: "memory");
    __builtin_amdgcn_sched_barrier(0);
    __builtin_amdgcn_s_setprio(1);
    #pragma unroll
    for (int fm=0;fm<4;++fm){
      acc[fm][0] = __builtin_amdgcn_mfma_f32_16x16x32_bf16(Ar[fm][0], Br[0][0], acc[fm][0], 0,0,0);
      acc[fm][0] = __builtin_amdgcn_mfma_f32_16x16x32_bf16(Ar[fm][1], Br[0][1], acc[fm][0], 0,0,0);
      acc[fm][1] = __builtin_amdgcn_mfma_f32_16x16x32_bf16(Ar[fm][0], Br[1][0], acc[fm][1], 0,0,0);
      acc[fm][1] = __builtin_amdgcn_mfma_f32_16x16x32_bf16(Ar[fm][1], Br[1][1], acc[fm][1], 0,0,0);
    }
    __builtin_amdgcn_s_setprio(0);
    __builtin_amdgcn_sched_barrier(0);
    __builtin_amdgcn_s_barrier();

    // ===== P1: B-hi(4) reads; stage t+2.A -> cur; MFMA; vmcnt(2) ===========
    #pragma unroll
    for (int nf=0;nf<2;++nf)
      #pragma unroll
      for (int kk=0;kk<2;++kk)
        Br[nf][kk] = frag(Bh, rbase + 32 + nf*16 + l15, kk*4 + hi);
    if (kt+2 < NT) stage(A, m0, (kt+2)*64, cur, 0);
    __builtin_amdgcn_sched_barrier(0);
    __builtin_amdgcn_s_barrier();
    asm volatile("s_waitcnt lgkmcnt(0)" ::: "memory");
    __builtin_amdgcn_sched_barrier(0);
    __builtin_amdgcn_s_setprio(1);
    #pragma unroll
    for (int fm=0;fm<4;++fm){
      acc[fm][2] = __builtin_amdgcn_mfma_f32_16x16x32_bf16(Ar[fm][0], Br[0][0], acc[fm][2], 0,0,0);
      acc[fm][2] = __builtin_amdgcn_mfma_f32_16x16x32_bf16(Ar[fm][1], Br[0][1], acc[fm][2], 0,0,0);
      acc[fm][3] = __builtin_amdgcn_mfma_f32_16x16x32_bf16(Ar[fm][0], Br[1][0], acc[fm][3], 0,0,0);
      acc[fm][3] = __builtin_amdgcn_mfma_f32_16x16x32_bf16(Ar[fm][1], Br[1][1], acc[fm][3], 0,0,0);
    }
    __builtin_amdgcn_s_setprio(0);
    if (kt+2 < NT)      asm volatile("s_waitcnt vmcnt(2)" ::: "memory");
    else if (kt+1 < NT) asm volatile("s_waitcnt vmcnt(0)" ::: "memory");
    __builtin_amdgcn_sched_barrier(0);
    __builtin_amdgcn_s_barrier();
  };

  for (int kt2 = 0; kt2 < NT; kt2 += 2){
    tile_body(kt2,     0);
    tile_body(kt2 + 1, 1);
  }

  // ---- epilogue ----
  if (MODE == 0 && (n0 >> 11) == 2){
    // V block: transpose 256(d) x 128(s) tile through LDS, coalesced vT store
    __builtin_amdgcn_s_barrier();
    unsigned short* trsp = smem;                  // [256 d][136] ushorts
    #pragma unroll
    for (int fm=0;fm<4;++fm){
      const int srow = wm*64 + fm*16 + hi*4;      // local s base (4 rows)
      #pragma unroll
      for (int p=0;p<4;++p){
        const int dcol = wn*64 + p*16 + l15;
        f32x4 v = acc[fm][p];
        ushort4 pk;
        pk.x=f2bf(v[0]); pk.y=f2bf(v[1]); pk.z=f2bf(v[2]); pk.w=f2bf(v[3]);
        *reinterpret_cast<ushort4*>(trsp + dcol*136 + srow) = pk;
      }
    }
    __syncthreads();
    const int bb  = m0 >> 11;
    const int ss0 = m0 & 2047;
    const size_t vrow = (size_t)(bb*2048 + (n0 - 4096));
    const int t = threadIdx.x;
    #pragma unroll
    for (int it=0; it<8; ++it){
      const int dl = it*32 + (t>>4);
      const int ch = t & 15;
      ushort8v val = *reinterpret_cast<const ushort8v*>(trsp + dl*136 + ch*8);
      *reinterpret_cast<ushort8v*>(vo + (vrow + dl)*SEQ + ss0 + ch*8) = val;
    }
  } else {
    #pragma unroll
    for (int fm=0;fm<4;++fm){
      const int row0 = m0 + wm*64 + fm*16 + (hi<<2);
      #pragma unroll
      for (int p=0;p<4;++p){
        const int col = n0 + wn*64 + p*16 + l15;
        f32x4 v = acc[fm][p];
        if (MODE == 1){
          #pragma unroll
          for (int r=0;r<4;++r) Cf[(size_t)(row0+r)*N + col] = v[r];
        } else {
          const int part = col >> 11;       // 0=q 1=k (v handled above)
          const int hh = (col >> 7) & 15;
          const int d  = col & 127;
          const int bb = row0 >> 11;
          const int ss = row0 & 2047;
          unsigned short* base = (part == 0 ? qo : ko)
                               + ((size_t)(bb*NHEADS+hh)*SEQ + ss)*HDIM + d;
          #pragma unroll
          for (int r=0;r<4;++r) base[r*HDIM] = f2bf(v[r]);
        }
      }
    }
  }
}

// ---------------- RoPE in-place on q,k -------------------------------------
__global__ void rope_kernel(unsigned short* __restrict__ qh, unsigned short* __restrict__ kh){
  const int idx = blockIdx.x * blockDim.x + threadIdx.x; // j(6)|s(11)|bh(5)|t(1)
  const int j  = idx & 63;
  const int s  = (idx >> 6) & 2047;
  const int bh = (idx >> 17) & 31;
  const int t  = idx >> 22;
  unsigned short* base = (t ? kh : qh) + ((size_t)bh*SEQ + s)*HDIM;
  const float x1 = bf2f(base[j]);
  const float x2 = bf2f(base[j+64]);
  const float inv = exp2f(-(float)j * (13.287712379549449f/64.f));
  const float ang = (float)s * inv;
  float sn, cs;
  sincosf(ang, &sn, &cs);
  float o1 = x1*cs - x2*sn;
  float o2 = x2*cs + x1*sn;
  const float QSCALE = 0.08838834764831845f * 1.4426950408889634f;
  if (t == 0){ o1 *= QSCALE; o2 *= QSCALE; }
  base[j]    = f2bf(o1);
  base[j+64] = f2bf(o2);
}

// ---------------- causal flash attention (v3, unchanged) -------------------
__global__ __launch_bounds__(256, 2) void attn_kernel(
    const unsigned short* __restrict__ qh,
    const unsigned short* __restrict__ kh,
    const unsigned short* __restrict__ vT,
    unsigned short* __restrict__ ao)
{
  __shared__ __align__(16) unsigned short Ks[2][64*128];
  __shared__ __align__(16) unsigned short Vs[2][128*64];
  __shared__ __align__(16) unsigned short Ps[4][16*64];

  const int lane = threadIdx.x & 63;
  const int wid  = threadIdx.x >> 6;
  const int hi   = lane >> 4;
  const int pr = blockIdx.x;
  const int bh = blockIdx.y;
  const int b_ = bh >> 4, h_ = bh & 15;

  const unsigned short* Qb = qh + (size_t)bh * SEQ * HDIM;
  const unsigned short* Kb = kh + (size_t)bh * SEQ * HDIM;
  const unsigned short* Vb = vT + (size_t)bh * HDIM * SEQ;

  auto stageKV = [&](int kg, int buf){
    #pragma unroll
    for (int i=0;i<4;++i){
      const int r  = (wid*4+i)*4 + (lane>>4);
      const int cb = ((lane&15)<<4) ^ ((r&7)<<4);
      gload_lds16(Kb + (size_t)(kg*64 + r)*HDIM + (cb>>1), &Ks[buf][0] + (wid*4+i)*512);
    }
    #pragma unroll
    for (int i=0;i<4;++i){
      const int d  = (wid*4+i)*8 + (lane>>3);
      const int cb = ((lane&7)<<4) ^ ((d&7)<<4);
      gload_lds16(Vb + (size_t)d*SEQ + kg*64 + (cb>>1), &Vs[buf][0] + (wid*4+i)*512);
    }
  };

  for (int ph = 0; ph < 2; ++ph){
    const int qt = ph ? (31 - pr) : pr;
    const int qrow0w = qt*QBLK + wid*16;

    bf16x8 qf[4];
    {
      const int qr = qrow0w + (lane & 15);
      #pragma unroll
      for (int ks = 0; ks < 4; ++ks)
        qf[ks] = *reinterpret_cast<const bf16x8*>(Qb + (size_t)qr*HDIM + ks*32 + hi*8);
    }

    f32x4 oacc[8];
    #pragma unroll
    for (int t=0;t<8;++t) oacc[t] = (f32x4){0.f,0.f,0.f,0.f};
    float mrun[4] = {-3.0e38f,-3.0e38f,-3.0e38f,-3.0e38f};
    float lrun[4] = {0.f,0.f,0.f,0.f};

    const int nkt = qt + 1;

    stageKV(0, 0);
    __syncthreads();

    for (int kt = 0; kt < nkt; ++kt){
      const int cur = kt & 1;
      if (kt + 1 < nkt) stageKV(kt + 1, cur ^ 1);

      if (kt*64 <= qrow0w + 15){
        f32x4 sacc[4];
        #pragma unroll
        for (int nt=0;nt<4;++nt) sacc[nt] = (f32x4){0.f,0.f,0.f,0.f};
        __builtin_amdgcn_s_setprio(1);
        #pragma unroll
        for (int nt=0;nt<4;++nt){
          const int krow = nt*16 + (lane&15);
          #pragma unroll
          for (int ks=0;ks<4;++ks){
            const int cb = (ks*64 + (hi<<4)) ^ ((krow&7)<<4);
            bf16x8 kf = *reinterpret_cast<const bf16x8*>(&Ks[cur][0] + krow*128 + (cb>>1));
            sacc[nt] = __builtin_amdgcn_mfma_f32_16x16x32_bf16(qf[ks], kf, sacc[nt], 0,0,0);
          }
        }
        __builtin_amdgcn_s_setprio(0);

        if (kt*64 + 63 > qrow0w){
          #pragma unroll
          for (int nt=0;nt<4;++nt){
            const int key = kt*64 + nt*16 + (lane&15);
            #pragma unroll
            for (int r=0;r<4;++r){
              const int qr = qrow0w + hi*4 + r;
              if (key > qr) sacc[nt][r] = -1.0e30f;
            }
          }
        }

        float fac[4];
        #pragma unroll
        for (int r=0;r<4;++r){
          float mx = fmaxf(fmaxf(sacc[0][r], sacc[1][r]),
                           fmaxf(sacc[2][r], sacc[3][r]));
          mx = rmax16(mx);
          const float mnew = fmaxf(mrun[r], mx);
          fac[r] = exp2f(mrun[r] - mnew);
          mrun[r] = mnew;
          float ps = 0.f;
          #pragma unroll
          for (int nt=0;nt<4;++nt){
            const float p = exp2f(sacc[nt][r] - mnew);
            sacc[nt][r] = p;
            ps += p;
          }
          ps = rsum16(ps);
          lrun[r] = lrun[r]*fac[r] + ps;
        }
        #pragma unroll
        for (int t=0;t<8;++t)
          #pragma unroll
          for (int r=0;r<4;++r) oacc[t][r] *= fac[r];

        char* pb = (char*)&Ps[wid][0];
        #pragma unroll
        for (int nt=0;nt<4;++nt){
          const int keyb = (nt*16 + (lane&15)) << 1;
          #pragma unroll
          for (int r=0;r<4;++r){
            const int prow = hi*4 + r;
            *(unsigned short*)(pb + prow*128 + (keyb ^ ((prow&7)<<4))) = f2bf(sacc[nt][r]);
          }
        }
        asm volatile("s_waitcnt lgkmcnt(0)" ::: "memory");
        __builtin_amdgcn_sched_barrier(0);

        bf16x8 pa[2];
        {
          const int prow = lane & 15;
          #pragma unroll
          for (int ks=0;ks<2;++ks){
            const int pcb = (ks*64 + (hi<<4)) ^ ((prow&7)<<4);
            pa[ks] = *reinterpret_cast<const bf16x8*>(pb + prow*128 + pcb);
          }
        }
        __builtin_amdgcn_s_setprio(1);
        #pragma unroll
        for (int ks=0;ks<2;++ks){
          #pragma unroll
          for (int t=0;t<8;++t){
            const int drow = t*16 + (lane&15);
            const int vcb = (ks*64 + (hi<<4)) ^ ((drow&7)<<4);
            bf16x8 vb = *reinterpret_cast<const bf16x8*>(&Vs[cur][0] + drow*64 + (vcb>>1));
            oacc[t] = __builtin_amdgcn_mfma_f32_16x16x32_bf16(pa[ks], vb, oacc[t], 0,0,0);
          }
        }
        __builtin_amdgcn_s_setprio(0);
      }

      __syncthreads();
    }

    float linv[4];
    #pragma unroll
    for (int r=0;r<4;++r) linv[r] = 1.0f / lrun[r];
    #pragma unroll
    for (int t=0;t<8;++t){
      const int col = h_*HDIM + t*16 + (lane&15);
      #pragma unroll
      for (int r=0;r<4;++r){
        const int s_ = qrow0w + hi*4 + r;
        ao[(size_t)(b_*SEQ + s_)*DMODEL + col] = f2bf(oacc[t][r] * linv[r]);
      }
    }
  }
}

// ---------------- launch ----------------
extern "C" void kernel_launch(void* const* d_in, const int* in_sizes, int n_in,
                              void* d_out, int out_size, void* d_ws, size_t ws_size,
                              hipStream_t stream)
{
  const float* x     = (const float*)d_in[0];
  const float* w_qkv = (const float*)d_in[1];
  const float* w_out = (const float*)d_in[2];
  float* out = (float*)d_out;

  unsigned short* xb    = (unsigned short*)d_ws;                 // 4096x2048
  unsigned short* wqkvb = xb    + (size_t)MTOT*DMODEL;           // 6144x2048
  unsigned short* woutb = wqkvb + (size_t)NQKV*DMODEL;           // 2048x2048
  unsigned short* qhb   = woutb + (size_t)DMODEL*DMODEL;         // (B,H,S,D)
  unsigned short* khb   = qhb   + (size_t)MTOT*DMODEL;           // (B,H,S,D)
  unsigned short* vtb   = khb   + (size_t)MTOT*DMODEL;           // (B,H,D,S)
  unsigned short* aob   = vtb   + (size_t)MTOT*DMODEL;           // 4096x2048

  hipLaunchKernelGGL(cast3_kernel, dim3(1024), dim3(256), 0, stream,
                     x, xb, MTOT*DMODEL, w_qkv, wqkvb, NQKV*DMODEL, w_out, woutb, DMODEL*DMODEL);
  hipLaunchKernelGGL((gemm2<0>), dim3(NQKV/256, MTOT/128), dim3(512), 0, stream,
                     xb, wqkvb, (float*)nullptr, qhb, khb, vtb, MTOT, NQKV, DMODEL);
  hipLaunchKernelGGL(rope_kernel, dim3((2*BATCH*NHEADS*SEQ*64)/256), dim3(256), 0, stream, qhb, khb);
  hipLaunchKernelGGL(attn_kernel, dim3(16, BATCH*NHEADS), dim3(256), 0, stream, qhb, khb, vtb, aob);
  hipLaunchKernelGGL((gemm2<1>), dim3(DMODEL/256, MTOT/128), dim3(512), 0, stream,
                     aob, woutb, out, (unsigned short*)nullptr, (unsigned short*)nullptr,
                     (unsigned short*)nullptr, MTOT, DMODEL, DMODEL);
}